// Round 19
// baseline (164.456 us; speedup 1.0000x reference)
//
#include <hip/hip_runtime.h>
#include <hip/hip_bf16.h>
#include <math.h>

static constexpr int DM = 1024;   // d_model
static constexpr int NH = 16;     // heads
static constexpr int DH = 64;     // head dim
static constexpr int QKV = 3 * DM;

typedef __attribute__((ext_vector_type(8))) short short8v;  // 8 bf16 = 4 VGPR
typedef __attribute__((ext_vector_type(4))) float f32x4;

__device__ inline short f2bf(float x) {
    __hip_bfloat16 h = __float2bfloat16(x);
    return *reinterpret_cast<short*>(&h);
}

// pack two f32 -> u32 of 2 bf16 (lo word = first arg), RNE
__device__ inline unsigned cvtpk(float a, float b) {
    unsigned r;
    asm("v_cvt_pk_bf16_f32 %0, %1, %2" : "=v"(r) : "v"(a), "v"(b));
    return r;
}

// pull f32 from srclane (0..63)
__device__ inline float bperm_f(int srclane, float v) {
    return __int_as_float(
        __builtin_amdgcn_ds_bpermute(srclane << 2, __float_as_int(v)));
}

// async global->LDS, 16B per lane.
__device__ inline void gload16(const void* g, void* l) {
    __builtin_amdgcn_global_load_lds(
        (const __attribute__((address_space(1))) unsigned int*)g,
        (__attribute__((address_space(3))) unsigned int*)l, 16, 0, 0);
}

// ---------------------------------------------------------------------------
// prep = fused {fp32->bf16 convert of all five inputs} U {cos/sin table}.
// ---------------------------------------------------------------------------
__global__ __launch_bounds__(256)
void prep(const float* __restrict__ x,  const float* __restrict__ wq,
          const float* __restrict__ wk, const float* __restrict__ wv,
          const float* __restrict__ wo, const int* __restrict__ pos,
          short* __restrict__ xh, short* __restrict__ wqkv,
          short* __restrict__ woh, float2* __restrict__ cst,
          int nx, int nw, int S) {
    const int t = blockIdx.x * 256 + threadIdx.x;
    const int nconv = (nx + 4 * nw) / 4;
    if (t < nconv) {
        const int i = t * 4;
        const float* src;
        short* dst;
        int off;
        if (i < nx)                { src = x;  dst = xh;            off = i; }
        else if (i < nx + nw)      { src = wq; dst = wqkv;          off = i - nx; }
        else if (i < nx + 2 * nw)  { src = wk; dst = wqkv + nw;     off = i - nx - nw; }
        else if (i < nx + 3 * nw)  { src = wv; dst = wqkv + 2 * nw; off = i - nx - 2 * nw; }
        else                       { src = wo; dst = woh;           off = i - nx - 3 * nw; }
        const float4 v = *(const float4*)(src + off);
        short4 o;
        o.x = f2bf(v.x); o.y = f2bf(v.y); o.z = f2bf(v.z); o.w = f2bf(v.w);
        *(short4*)(dst + off) = o;
    } else {
        const int j = t - nconv;
        if (j >= S * 32) return;
        const int s = j >> 5, k = j & 31;
        const float ang = (float)pos[s] * powf(10000.0f, -(float)k * (1.0f / 32.0f));
        cst[j] = make_float2(cosf(ang), sinf(ang));
    }
}

// ---------------------------------------------------------------------------
// bf16 MFMA GEMM, m97 structure + XCD-aware block swizzle (R18, passing).
// ---------------------------------------------------------------------------
template <int BF16OUT>
__global__ __launch_bounds__(256)
void gemm_bt_mfma(const short* __restrict__ A, const short* __restrict__ B,
                  void* __restrict__ Cv, int M, int N, int K, int gy) {
    __shared__ __align__(16) short As[128 * 32];
    __shared__ __align__(16) short Bs[128 * 32];
    const int tid = threadIdx.x;
    const int w = tid >> 6, l = tid & 63;
    const int lo = l & 15, hi = l >> 4;
    const int wr = w >> 1, wc = w & 1;

    const int flat = blockIdx.x;
    const int cpx = gridDim.x >> 3;
    const int s = (flat & 7) * cpx + (flat >> 3);
    const int by = s % gy, bx = s / gy;
    const size_t m0 = (size_t)by * 128;
    const size_t n0 = (size_t)bx * 128;

    const int cr = (w * 2) * 16 + (l >> 2);
    const int cc = (l & 3) * 8;
    const short* Ag0 = A + (m0 + cr) * K + cc;
    const short* Ag1 = Ag0 + (size_t)16 * K;
    const short* Bg0 = B + (n0 + cr) * K + cc;
    const short* Bg1 = Bg0 + (size_t)16 * K;
    short* As0 = As + (w * 2) * 512;
    short* As1 = As0 + 512;
    short* Bs0 = Bs + (w * 2) * 512;
    short* Bs1 = Bs0 + 512;

    f32x4 acc[4][4];
    #pragma unroll
    for (int mi = 0; mi < 4; ++mi)
        #pragma unroll
        for (int nj = 0; nj < 4; ++nj)
            acc[mi][nj] = (f32x4){0.f, 0.f, 0.f, 0.f};

    const int aoff = (wr * 64 + lo) * 32 + hi * 8;
    const int boff = (wc * 64 + lo) * 32 + hi * 8;

    for (int k0 = 0; k0 < K; k0 += 32) {
        __syncthreads();
        gload16(Ag0 + k0, As0);
        gload16(Ag1 + k0, As1);
        gload16(Bg0 + k0, Bs0);
        gload16(Bg1 + k0, Bs1);
        __syncthreads();
        short8v af[4], bf[4];
        #pragma unroll
        for (int mi = 0; mi < 4; ++mi)
            af[mi] = *(const short8v*)&As[aoff + mi * 16 * 32];
        #pragma unroll
        for (int nj = 0; nj < 4; ++nj)
            bf[nj] = *(const short8v*)&Bs[boff + nj * 16 * 32];
        #pragma unroll
        for (int mi = 0; mi < 4; ++mi)
            #pragma unroll
            for (int nj = 0; nj < 4; ++nj)
                acc[mi][nj] = __builtin_amdgcn_mfma_f32_16x16x32_bf16(
                    af[mi], bf[nj], acc[mi][nj], 0, 0, 0);
    }

    const size_t mbase = m0 + wr * 64 + hi * 4;
    const size_t nbase = n0 + wc * 64 + lo;
    #pragma unroll
    for (int mi = 0; mi < 4; ++mi)
        #pragma unroll
        for (int nj = 0; nj < 4; ++nj)
            #pragma unroll
            for (int rg = 0; rg < 4; ++rg) {
                const size_t m = mbase + mi * 16 + rg;
                const size_t n = nbase + nj * 16;
                if (BF16OUT)
                    ((short*)Cv)[m * N + n] = f2bf(acc[mi][nj][rg]);
                else
                    ((float*)Cv)[m * N + n] = acc[mi][nj][rg];
            }
}

// ---------------------------------------------------------------------------
// rope_vt = fused {RoPE on Q/K} U {V -> blocked-transposed Vt2}. (passing)
// ---------------------------------------------------------------------------
__global__ __launch_bounds__(256)
void rope_vt(const short* __restrict__ QKVr, const float2* __restrict__ cst,
             short* __restrict__ Qh, short* __restrict__ Kh,
             short* __restrict__ Vt, int S, int rows, int ropeBlk) {
    __shared__ __align__(16) short T[64][72];
    const int tid = threadIdx.x;

    if ((int)blockIdx.x < ropeBlk) {
        int idx = blockIdx.x * 256 + tid;
        const int per = rows * (DM / 2);
        bool isK = false;
        if (idx >= per) { idx -= per; isK = true; }
        if (idx >= per) return;
        const int row = idx >> 9;
        const int rem = idx & 511;
        const int h = rem >> 5, k = rem & 31;
        const int b = row / S, sr = row - b * S;
        const unsigned pin = *(const unsigned*)(QKVr + (size_t)row * QKV +
                                                (isK ? DM : 0) + h * DH + 2 * k);
        const float x0 = __uint_as_float(pin << 16);
        const float x1 = __uint_as_float(pin & 0xffff0000u);
        const float2 cs = cst[sr * 32 + k];
        float y0 = cs.x * x0 - cs.y * x1;
        float y1 = cs.y * x0 + cs.x * x1;
        if (!isK) {
            const float qs = 0.125f * 1.4426950408889634f;
            y0 *= qs; y1 *= qs;
        }
        short* dst = (isK ? Kh : Qh) + ((size_t)(b * NH + h) * S + sr) * DH + 2 * k;
        *(unsigned*)dst = ((unsigned)(unsigned short)f2bf(y1) << 16)
                        | (unsigned short)f2bf(y0);
    } else {
        const int vb = blockIdx.x - ropeBlk;
        const int nsx = S >> 6;
        const int sx = vb % nsx, bh = vb / nsx;
        const int b = bh / NH, h = bh - b * NH;
        const int s0 = sx * 64;
        const int r = tid >> 2, seg = (tid & 3) * 16;
        const short* src = QKVr + (size_t)(b * S + s0 + r) * QKV + 2 * DM + h * DH + seg;
        const short8v a0 = *(const short8v*)(src);
        const short8v a1 = *(const short8v*)(src + 8);
        #pragma unroll
        for (int j = 0; j < 8; ++j) T[seg + j][r] = a0[j];
        #pragma unroll
        for (int j = 0; j < 8; ++j) T[seg + 8 + j][r] = a1[j];
        __syncthreads();
        const int d = tid >> 2, q = tid & 3;
        short* Vp2 = Vt + (size_t)bh * DH * S;
        #pragma unroll
        for (int j = 0; j < 2; ++j) {
            const int sbl = q * 2 + j;
            const uint4 v = *(const uint4*)&T[d][sbl * 8];
            *(uint4*)&Vp2[(((size_t)(s0 >> 3) + sbl) * 64 + d) * 8] = v;
        }
    }
}

// ---------------------------------------------------------------------------
// MFMA flash attention, R19 = R18 with V loads moved AFTER softmax (before
// the lgkmcnt fence): vf no longer live across QK^T+softmax (the register-
// pressure peak), its L2 latency hides under fence + pa reads + row-sum
// MFMAs. All math and layouts identical to R17/R18 (passing).
// ---------------------------------------------------------------------------
__global__ __launch_bounds__(256)
void attn_mfma(const short* __restrict__ Qh, const short* __restrict__ Kh,
               const short* __restrict__ Vt, short* __restrict__ Oh,
               int S, int bpb) {
    __shared__ __align__(16) unsigned P2[4][2][16][36];   // 18432 B
    __shared__ __align__(16) float MB[2][64][24];         // 12288 B

    const int tid = threadIdx.x;
    const int w = tid >> 6, l = tid & 63;
    const int pw = w >> 1, half = w & 1;
    const int lo = l & 15, hi = l >> 4;
    const int T = S >> 4;

    const int flat = blockIdx.x;
    const int bh3 = flat & 7;
    const int r = flat >> 3;
    const int grp = r / bpb, blk = r - grp * bpb;
    const int bh = grp * 8 + bh3;
    const int b = bh >> 4, h = bh & 15;          // NH = 16
    const int p = blk * 2 + pw;

    const int q0B = (T - 1 - p) << 4;
    const int q0F = p << 4;
    const int nkbB = (q0B + 79) >> 6;
    const int nkbF = (q0F + 79) >> 6;

    const short* Qp = Qh + (size_t)bh * S * DH;

    const short8v qB0 = *(const short8v*)(Qp + (size_t)(q0B + lo) * DH + hi * 8);
    const short8v qB1 = *(const short8v*)(Qp + (size_t)(q0B + lo) * DH + 32 + hi * 8);
    const short8v qF0 = *(const short8v*)(Qp + (size_t)(q0F + lo) * DH + hi * 8);
    const short8v qF1 = *(const short8v*)(Qp + (size_t)(q0F + lo) * DH + 32 + hi * 8);

    // running fragment base pointers (advance 8192 shorts per kb+=2 step)
    const short* kptr = Kh + (size_t)bh * S * DH
                      + (size_t)(half * 64 + lo) * DH + hi * 8;
    const short* vptr = Vt + (size_t)bh * DH * S
                      + (size_t)(half * 8 + hi) * 512 + lo * 8;

    short8v ones;
    #pragma unroll
    for (int i = 0; i < 8; ++i) ones[i] = (short)0x3F80;   // bf16 1.0

    f32x4 oB[4], oF[4];
    f32x4 laB = (f32x4){0.f, 0.f, 0.f, 0.f};
    f32x4 laF = (f32x4){0.f, 0.f, 0.f, 0.f};
    float mB = -INFINITY, mF = -INFINITY;
    #pragma unroll
    for (int i = 0; i < 4; ++i) {
        oB[i] = (f32x4){0.f, 0.f, 0.f, 0.f};
        oF[i] = (f32x4){0.f, 0.f, 0.f, 0.f};
    }
    const f32x4 z = (f32x4){0.f, 0.f, 0.f, 0.f};

    auto softmaxTile = [&](const f32x4 (&s)[4], float& m, f32x4 (&o)[4],
                           f32x4& la, bool masked, int q0, int kvb, int tsel) {
        float pv[16];
        float bm = -INFINITY;
        const int lim = q0 + lo - kvb;
        #pragma unroll
        for (int kt = 0; kt < 4; ++kt)
            #pragma unroll
            for (int rg = 0; rg < 4; ++rg) {
                float v = s[kt][rg];
                if (masked && (kt * 16 + hi * 4 + rg > lim)) v = -INFINITY;
                pv[kt * 4 + rg] = v;
                bm = fmaxf(bm, v);
            }
        bm = fmaxf(bm, __shfl_xor(bm, 16));
        bm = fmaxf(bm, __shfl_xor(bm, 32));
        if (__any(bm > m + 8.0f)) {
            const float mn = fmaxf(m, bm);
            const float c = exp2f(m - mn);
            m = mn;
            #pragma unroll
            for (int rg = 0; rg < 4; ++rg) {
                const float cr = bperm_f(hi * 4 + rg, c);
                la[rg] *= cr;
                #pragma unroll
                for (int dt = 0; dt < 4; ++dt) o[dt][rg] *= cr;
            }
        }
        #pragma unroll
        for (int kt = 0; kt < 4; ++kt) {
            uint2 wv;
            wv.x = cvtpk(exp2f(pv[kt * 4 + 0] - m), exp2f(pv[kt * 4 + 1] - m));
            wv.y = cvtpk(exp2f(pv[kt * 4 + 2] - m), exp2f(pv[kt * 4 + 3] - m));
            *(uint2*)&P2[w][tsel][lo][kt * 8 + hi * 2] = wv;
        }
    };

    for (int kb = half; kb < nkbB; kb += 2) {
        const int kvb = kb * 64;
        const bool actF = kb < nkbF;

        // ---- K fragments: base + constant offsets
        short8v kf0[4], kf1[4];
        #pragma unroll
        for (int kt = 0; kt < 4; ++kt) {
            kf0[kt] = *(const short8v*)(kptr + kt * 1024);
            kf1[kt] = *(const short8v*)(kptr + kt * 1024 + 32);
        }

        // ---- swapped QK^T, both tiles
        f32x4 sB[4], sF[4];
        #pragma unroll
        for (int kt = 0; kt < 4; ++kt) {
            f32x4 a = z;
            a = __builtin_amdgcn_mfma_f32_16x16x32_bf16(kf0[kt], qB0, a, 0, 0, 0);
            a = __builtin_amdgcn_mfma_f32_16x16x32_bf16(kf1[kt], qB1, a, 0, 0, 0);
            sB[kt] = a;
        }
        if (actF) {
            #pragma unroll
            for (int kt = 0; kt < 4; ++kt) {
                f32x4 a = z;
                a = __builtin_amdgcn_mfma_f32_16x16x32_bf16(kf0[kt], qF0, a, 0, 0, 0);
                a = __builtin_amdgcn_mfma_f32_16x16x32_bf16(kf1[kt], qF1, a, 0, 0, 0);
                sF[kt] = a;
            }
        }

        softmaxTile(sB, mB, oB, laB, kb == nkbB - 1, q0B, kvb, 0);
        if (actF) softmaxTile(sF, mF, oF, laF, kb == nkbF - 1, q0F, kvb, 1);

        // ---- V fragments issued HERE: not live across QK/softmax; latency
        // hides under fence + pa reads + row-sum MFMAs.
        short8v vf0[4], vf1[4];
        #pragma unroll
        for (int dt = 0; dt < 4; ++dt) {
            vf0[dt] = *(const short8v*)(vptr + dt * 128);
            vf1[dt] = *(const short8v*)(vptr + dt * 128 + 2048);
        }

        asm volatile("s_waitcnt lgkmcnt(0)" ::: "memory");
        const short8v paB0 = *(const short8v*)&P2[w][0][lo][hi * 4];
        const short8v paB1 = *(const short8v*)&P2[w][0][lo][16 + hi * 4];

        laB = __builtin_amdgcn_mfma_f32_16x16x32_bf16(paB0, ones, laB, 0, 0, 0);
        laB = __builtin_amdgcn_mfma_f32_16x16x32_bf16(paB1, ones, laB, 0, 0, 0);
        #pragma unroll
        for (int dt = 0; dt < 4; ++dt) {
            oB[dt] = __builtin_amdgcn_mfma_f32_16x16x32_bf16(paB0, vf0[dt], oB[dt], 0, 0, 0);
            oB[dt] = __builtin_amdgcn_mfma_f32_16x16x32_bf16(paB1, vf1[dt], oB[dt], 0, 0, 0);
        }
        if (actF) {
            const short8v paF0 = *(const short8v*)&P2[w][1][lo][hi * 4];
            const short8v paF1 = *(const short8v*)&P2[w][1][lo][16 + hi * 4];
            laF = __builtin_amdgcn_mfma_f32_16x16x32_bf16(paF0, ones, laF, 0, 0, 0);
            laF = __builtin_amdgcn_mfma_f32_16x16x32_bf16(paF1, ones, laF, 0, 0, 0);
            #pragma unroll
            for (int dt = 0; dt < 4; ++dt) {
                oF[dt] = __builtin_amdgcn_mfma_f32_16x16x32_bf16(paF0, vf0[dt], oF[dt], 0, 0, 0);
                oF[dt] = __builtin_amdgcn_mfma_f32_16x16x32_bf16(paF1, vf1[dt], oF[dt], 0, 0, 0);
            }
        }

        kptr += 8192;
        vptr += 8192;
    }

    float mBr[4], mFr[4];
    #pragma unroll
    for (int rg = 0; rg < 4; ++rg) {
        mBr[rg] = bperm_f(hi * 4 + rg, mB);
        mFr[rg] = bperm_f(hi * 4 + rg, mF);
    }

#define STORE_TILE(OT, MT, LAT)                                            \
    do {                                                                   \
        f32x4* dst = (f32x4*)&MB[pw][l][0];                                \
        dst[0] = OT[0]; dst[1] = OT[1]; dst[2] = OT[2]; dst[3] = OT[3];    \
        dst[4] = (f32x4){MT[0], MT[1], MT[2], MT[3]};                      \
        dst[5] = LAT;                                                      \
    } while (0)

#define MERGE_TILE(OT, MT, LAT, Q0T)                                       \
    do {                                                                   \
        const f32x4* src = (const f32x4*)&MB[pw][l][0];                    \
        const f32x4 o1_0 = src[0], o1_1 = src[1], o1_2 = src[2], o1_3 = src[3]; \
        const f32x4 m1 = src[4];                                           \
        const f32x4 la1 = src[5];                                          \
        short* Op = Oh + (size_t)(b * S + (Q0T)) * DM + h * DH;            \
        _Pragma("unroll")                                                  \
        for (int rg = 0; rg < 4; ++rg) {                                   \
            const float mst = fmaxf(MT[rg], m1[rg]);                       \
            const float c0 = exp2f(MT[rg] - mst);                          \
            const float c1 = exp2f(m1[rg] - mst);                          \
            const float iv = 1.0f / (LAT[rg] * c0 + la1[rg] * c1);         \
            Op[(size_t)(hi * 4 + rg) * DM +  0 + lo] = f2bf((OT[0][rg] * c0 + o1_0[rg] * c1) * iv); \
            Op[(size_t)(hi * 4 + rg) * DM + 16 + lo] = f2bf((OT[1][rg] * c0 + o1_1[rg] * c1) * iv); \
            Op[(size_t)(hi * 4 + rg) * DM + 32 + lo] = f2bf((OT[2][rg] * c0 + o1_2[rg] * c1) * iv); \
            Op[(size_t)(hi * 4 + rg) * DM + 48 + lo] = f2bf((OT[3][rg] * c0 + o1_3[rg] * c1) * iv); \
        }                                                                  \
    } while (0)

    __syncthreads();
    if (half == 1) STORE_TILE(oB, mBr, laB);
    __syncthreads();
    if (half == 0) MERGE_TILE(oB, mBr, laB, q0B);
    __syncthreads();
    if (half == 1) STORE_TILE(oF, mFr, laF);
    __syncthreads();
    if (half == 0) MERGE_TILE(oF, mFr, laF, q0F);
#undef STORE_TILE
#undef MERGE_TILE
}

// ---------------------------------------------------------------------------
extern "C" void kernel_launch(void* const* d_in, const int* in_sizes, int n_in,
                              void* d_out, int out_size, void* d_ws, size_t ws_size,
                              hipStream_t stream) {
    const float* x  = (const float*)d_in[0];
    const int*  pos = (const int*)d_in[1];
    const float* wq = (const float*)d_in[2];
    const float* wk = (const float*)d_in[3];
    const float* wv = (const float*)d_in[4];
    const float* wo = (const float*)d_in[5];
    float* out = (float*)d_out;

    const int S = in_sizes[1];              // 2048
    const int rows = in_sizes[0] / DM;      // B*S
    const int Bb = rows / S;

    short* xh   = (short*)d_ws;
    short* wqkv = xh + (size_t)rows * DM;
    short* woh  = wqkv + (size_t)QKV * DM;
    short* QKVr = woh + (size_t)DM * DM;
    short* Qh   = QKVr + (size_t)rows * QKV;
    short* Kh   = Qh + (size_t)rows * DM;
    short* Vt   = Kh + (size_t)rows * DM;
    short* Oh   = Vt + (size_t)rows * DM;
    float2* cst = (float2*)(Oh + (size_t)rows * DM);

    const int nx = rows * DM;
    const int nw = DM * DM;
    const int nprep = (nx + 4 * nw) / 4 + S * 32;
    prep<<<(nprep + 255) / 256, 256, 0, stream>>>(
        x, wq, wk, wv, wo, pos, xh, wqkv, woh, cst, nx, nw, S);

    gemm_bt_mfma<1><<<dim3((QKV / 128) * (rows / 128)), 256, 0, stream>>>(
        xh, wqkv, QKVr, rows, QKV, DM, rows / 128);

    const int ropeBlk = (rows * DM + 255) / 256;
    const int vtBlk = (S / 64) * (Bb * NH);
    rope_vt<<<ropeBlk + vtBlk, 256, 0, stream>>>(
        QKVr, cst, Qh, Kh, Vt, S, rows, ropeBlk);

    const int Tq = S / 16;
    const int bpb = Tq / 4;
    const int nbh = Bb * NH;
    attn_mfma<<<dim3(nbh * bpb), 256, 0, stream>>>(Qh, Kh, Vt, Oh, S, bpb);

    gemm_bt_mfma<0><<<dim3((DM / 128) * (rows / 128)), 256, 0, stream>>>(
        Oh, woh, out, rows, DM, DM, rows / 128);
}

// Round 20
// 163.428 us; speedup vs baseline: 1.0063x; 1.0063x over previous
//
#include <hip/hip_runtime.h>
#include <hip/hip_bf16.h>
#include <math.h>

static constexpr int DM = 1024;   // d_model
static constexpr int NH = 16;     // heads
static constexpr int DH = 64;     // head dim
static constexpr int QKV = 3 * DM;

typedef __attribute__((ext_vector_type(8))) short short8v;  // 8 bf16 = 4 VGPR
typedef __attribute__((ext_vector_type(4))) float f32x4;

__device__ inline short f2bf(float x) {
    __hip_bfloat16 h = __float2bfloat16(x);
    return *reinterpret_cast<short*>(&h);
}

// pack two f32 -> u32 of 2 bf16 (lo word = first arg), RNE
__device__ inline unsigned cvtpk(float a, float b) {
    unsigned r;
    asm("v_cvt_pk_bf16_f32 %0, %1, %2" : "=v"(r) : "v"(a), "v"(b));
    return r;
}

// pull f32 from srclane (0..63)
__device__ inline float bperm_f(int srclane, float v) {
    return __int_as_float(
        __builtin_amdgcn_ds_bpermute(srclane << 2, __float_as_int(v)));
}

// async global->LDS, 16B per lane.
__device__ inline void gload16(const void* g, void* l) {
    __builtin_amdgcn_global_load_lds(
        (const __attribute__((address_space(1))) unsigned int*)g,
        (__attribute__((address_space(3))) unsigned int*)l, 16, 0, 0);
}

// ---------------------------------------------------------------------------
// prep = fused {fp32->bf16 convert of all five inputs} U {cos/sin table}.
// ---------------------------------------------------------------------------
__global__ __launch_bounds__(256)
void prep(const float* __restrict__ x,  const float* __restrict__ wq,
          const float* __restrict__ wk, const float* __restrict__ wv,
          const float* __restrict__ wo, const int* __restrict__ pos,
          short* __restrict__ xh, short* __restrict__ wqkv,
          short* __restrict__ woh, float2* __restrict__ cst,
          int nx, int nw, int S) {
    const int t = blockIdx.x * 256 + threadIdx.x;
    const int nconv = (nx + 4 * nw) / 4;
    if (t < nconv) {
        const int i = t * 4;
        const float* src;
        short* dst;
        int off;
        if (i < nx)                { src = x;  dst = xh;            off = i; }
        else if (i < nx + nw)      { src = wq; dst = wqkv;          off = i - nx; }
        else if (i < nx + 2 * nw)  { src = wk; dst = wqkv + nw;     off = i - nx - nw; }
        else if (i < nx + 3 * nw)  { src = wv; dst = wqkv + 2 * nw; off = i - nx - 2 * nw; }
        else                       { src = wo; dst = woh;           off = i - nx - 3 * nw; }
        const float4 v = *(const float4*)(src + off);
        short4 o;
        o.x = f2bf(v.x); o.y = f2bf(v.y); o.z = f2bf(v.z); o.w = f2bf(v.w);
        *(short4*)(dst + off) = o;
    } else {
        const int j = t - nconv;
        if (j >= S * 32) return;
        const int s = j >> 5, k = j & 31;
        const float ang = (float)pos[s] * powf(10000.0f, -(float)k * (1.0f / 32.0f));
        cst[j] = make_float2(cosf(ang), sinf(ang));
    }
}

// ---------------------------------------------------------------------------
// bf16 MFMA GEMM, m97 structure + XCD-aware block swizzle (passing).
// ---------------------------------------------------------------------------
template <int BF16OUT>
__global__ __launch_bounds__(256)
void gemm_bt_mfma(const short* __restrict__ A, const short* __restrict__ B,
                  void* __restrict__ Cv, int M, int N, int K, int gy) {
    __shared__ __align__(16) short As[128 * 32];
    __shared__ __align__(16) short Bs[128 * 32];
    const int tid = threadIdx.x;
    const int w = tid >> 6, l = tid & 63;
    const int lo = l & 15, hi = l >> 4;
    const int wr = w >> 1, wc = w & 1;

    const int flat = blockIdx.x;
    const int cpx = gridDim.x >> 3;
    const int s = (flat & 7) * cpx + (flat >> 3);
    const int by = s % gy, bx = s / gy;
    const size_t m0 = (size_t)by * 128;
    const size_t n0 = (size_t)bx * 128;

    const int cr = (w * 2) * 16 + (l >> 2);
    const int cc = (l & 3) * 8;
    const short* Ag0 = A + (m0 + cr) * K + cc;
    const short* Ag1 = Ag0 + (size_t)16 * K;
    const short* Bg0 = B + (n0 + cr) * K + cc;
    const short* Bg1 = Bg0 + (size_t)16 * K;
    short* As0 = As + (w * 2) * 512;
    short* As1 = As0 + 512;
    short* Bs0 = Bs + (w * 2) * 512;
    short* Bs1 = Bs0 + 512;

    f32x4 acc[4][4];
    #pragma unroll
    for (int mi = 0; mi < 4; ++mi)
        #pragma unroll
        for (int nj = 0; nj < 4; ++nj)
            acc[mi][nj] = (f32x4){0.f, 0.f, 0.f, 0.f};

    const int aoff = (wr * 64 + lo) * 32 + hi * 8;
    const int boff = (wc * 64 + lo) * 32 + hi * 8;

    for (int k0 = 0; k0 < K; k0 += 32) {
        __syncthreads();
        gload16(Ag0 + k0, As0);
        gload16(Ag1 + k0, As1);
        gload16(Bg0 + k0, Bs0);
        gload16(Bg1 + k0, Bs1);
        __syncthreads();
        short8v af[4], bf[4];
        #pragma unroll
        for (int mi = 0; mi < 4; ++mi)
            af[mi] = *(const short8v*)&As[aoff + mi * 16 * 32];
        #pragma unroll
        for (int nj = 0; nj < 4; ++nj)
            bf[nj] = *(const short8v*)&Bs[boff + nj * 16 * 32];
        #pragma unroll
        for (int mi = 0; mi < 4; ++mi)
            #pragma unroll
            for (int nj = 0; nj < 4; ++nj)
                acc[mi][nj] = __builtin_amdgcn_mfma_f32_16x16x32_bf16(
                    af[mi], bf[nj], acc[mi][nj], 0, 0, 0);
    }

    const size_t mbase = m0 + wr * 64 + hi * 4;
    const size_t nbase = n0 + wc * 64 + lo;
    #pragma unroll
    for (int mi = 0; mi < 4; ++mi)
        #pragma unroll
        for (int nj = 0; nj < 4; ++nj)
            #pragma unroll
            for (int rg = 0; rg < 4; ++rg) {
                const size_t m = mbase + mi * 16 + rg;
                const size_t n = nbase + nj * 16;
                if (BF16OUT)
                    ((short*)Cv)[m * N + n] = f2bf(acc[mi][nj][rg]);
                else
                    ((float*)Cv)[m * N + n] = acc[mi][nj][rg];
            }
}

// ---------------------------------------------------------------------------
// rope_vt = fused {RoPE on Q/K} U {V -> blocked-transposed Vt2}. (passing)
// ---------------------------------------------------------------------------
__global__ __launch_bounds__(256)
void rope_vt(const short* __restrict__ QKVr, const float2* __restrict__ cst,
             short* __restrict__ Qh, short* __restrict__ Kh,
             short* __restrict__ Vt, int S, int rows, int ropeBlk) {
    __shared__ __align__(16) short T[64][72];
    const int tid = threadIdx.x;

    if ((int)blockIdx.x < ropeBlk) {
        int idx = blockIdx.x * 256 + tid;
        const int per = rows * (DM / 2);
        bool isK = false;
        if (idx >= per) { idx -= per; isK = true; }
        if (idx >= per) return;
        const int row = idx >> 9;
        const int rem = idx & 511;
        const int h = rem >> 5, k = rem & 31;
        const int b = row / S, sr = row - b * S;
        const unsigned pin = *(const unsigned*)(QKVr + (size_t)row * QKV +
                                                (isK ? DM : 0) + h * DH + 2 * k);
        const float x0 = __uint_as_float(pin << 16);
        const float x1 = __uint_as_float(pin & 0xffff0000u);
        const float2 cs = cst[sr * 32 + k];
        float y0 = cs.x * x0 - cs.y * x1;
        float y1 = cs.y * x0 + cs.x * x1;
        if (!isK) {
            const float qs = 0.125f * 1.4426950408889634f;
            y0 *= qs; y1 *= qs;
        }
        short* dst = (isK ? Kh : Qh) + ((size_t)(b * NH + h) * S + sr) * DH + 2 * k;
        *(unsigned*)dst = ((unsigned)(unsigned short)f2bf(y1) << 16)
                        | (unsigned short)f2bf(y0);
    } else {
        const int vb = blockIdx.x - ropeBlk;
        const int nsx = S >> 6;
        const int sx = vb % nsx, bh = vb / nsx;
        const int b = bh / NH, h = bh - b * NH;
        const int s0 = sx * 64;
        const int r = tid >> 2, seg = (tid & 3) * 16;
        const short* src = QKVr + (size_t)(b * S + s0 + r) * QKV + 2 * DM + h * DH + seg;
        const short8v a0 = *(const short8v*)(src);
        const short8v a1 = *(const short8v*)(src + 8);
        #pragma unroll
        for (int j = 0; j < 8; ++j) T[seg + j][r] = a0[j];
        #pragma unroll
        for (int j = 0; j < 8; ++j) T[seg + 8 + j][r] = a1[j];
        __syncthreads();
        const int d = tid >> 2, q = tid & 3;
        short* Vp2 = Vt + (size_t)bh * DH * S;
        #pragma unroll
        for (int j = 0; j < 2; ++j) {
            const int sbl = q * 2 + j;
            const uint4 v = *(const uint4*)&T[d][sbl * 8];
            *(uint4*)&Vp2[(((size_t)(s0 >> 3) + sbl) * 64 + d) * 8] = v;
        }
    }
}

// ---------------------------------------------------------------------------
// MFMA flash attention, R20 = R19 + (a) s_setprio(1) around MFMA clusters
// (T5: waves here are phase-diverse — independent blocks, KV-split halves
// at different kb — the m191 regime where setprio pays), (b) kb loop split
// into joint (both tiles) / solo (B only) phases, hoisting the actF
// predication out of ~half the iterations. Math identical to R19 (passing).
// ---------------------------------------------------------------------------
__global__ __launch_bounds__(256)
void attn_mfma(const short* __restrict__ Qh, const short* __restrict__ Kh,
               const short* __restrict__ Vt, short* __restrict__ Oh,
               int S, int bpb) {
    __shared__ __align__(16) unsigned P2[4][2][16][36];   // 18432 B
    __shared__ __align__(16) float MB[2][64][24];         // 12288 B

    const int tid = threadIdx.x;
    const int w = tid >> 6, l = tid & 63;
    const int pw = w >> 1, half = w & 1;
    const int lo = l & 15, hi = l >> 4;
    const int T = S >> 4;

    const int flat = blockIdx.x;
    const int bh3 = flat & 7;
    const int r = flat >> 3;
    const int grp = r / bpb, blk = r - grp * bpb;
    const int bh = grp * 8 + bh3;
    const int b = bh >> 4, h = bh & 15;          // NH = 16
    const int p = blk * 2 + pw;

    const int q0B = (T - 1 - p) << 4;
    const int q0F = p << 4;
    const int nkbB = (q0B + 79) >> 6;
    const int nkbF = (q0F + 79) >> 6;

    const short* Qp = Qh + (size_t)bh * S * DH;

    const short8v qB0 = *(const short8v*)(Qp + (size_t)(q0B + lo) * DH + hi * 8);
    const short8v qB1 = *(const short8v*)(Qp + (size_t)(q0B + lo) * DH + 32 + hi * 8);
    const short8v qF0 = *(const short8v*)(Qp + (size_t)(q0F + lo) * DH + hi * 8);
    const short8v qF1 = *(const short8v*)(Qp + (size_t)(q0F + lo) * DH + 32 + hi * 8);

    const short* kptr = Kh + (size_t)bh * S * DH
                      + (size_t)(half * 64 + lo) * DH + hi * 8;
    const short* vptr = Vt + (size_t)bh * DH * S
                      + (size_t)(half * 8 + hi) * 512 + lo * 8;

    short8v ones;
    #pragma unroll
    for (int i = 0; i < 8; ++i) ones[i] = (short)0x3F80;   // bf16 1.0

    f32x4 oB[4], oF[4];
    f32x4 laB = (f32x4){0.f, 0.f, 0.f, 0.f};
    f32x4 laF = (f32x4){0.f, 0.f, 0.f, 0.f};
    float mB = -INFINITY, mF = -INFINITY;
    #pragma unroll
    for (int i = 0; i < 4; ++i) {
        oB[i] = (f32x4){0.f, 0.f, 0.f, 0.f};
        oF[i] = (f32x4){0.f, 0.f, 0.f, 0.f};
    }
    const f32x4 z = (f32x4){0.f, 0.f, 0.f, 0.f};

    auto softmaxTile = [&](const f32x4 (&s)[4], float& m, f32x4 (&o)[4],
                           f32x4& la, bool masked, int q0, int kvb, int tsel) {
        float pv[16];
        float bm = -INFINITY;
        const int lim = q0 + lo - kvb;
        #pragma unroll
        for (int kt = 0; kt < 4; ++kt)
            #pragma unroll
            for (int rg = 0; rg < 4; ++rg) {
                float v = s[kt][rg];
                if (masked && (kt * 16 + hi * 4 + rg > lim)) v = -INFINITY;
                pv[kt * 4 + rg] = v;
                bm = fmaxf(bm, v);
            }
        bm = fmaxf(bm, __shfl_xor(bm, 16));
        bm = fmaxf(bm, __shfl_xor(bm, 32));
        if (__any(bm > m + 8.0f)) {
            const float mn = fmaxf(m, bm);
            const float c = exp2f(m - mn);
            m = mn;
            #pragma unroll
            for (int rg = 0; rg < 4; ++rg) {
                const float cr = bperm_f(hi * 4 + rg, c);
                la[rg] *= cr;
                #pragma unroll
                for (int dt = 0; dt < 4; ++dt) o[dt][rg] *= cr;
            }
        }
        #pragma unroll
        for (int kt = 0; kt < 4; ++kt) {
            uint2 wv;
            wv.x = cvtpk(exp2f(pv[kt * 4 + 0] - m), exp2f(pv[kt * 4 + 1] - m));
            wv.y = cvtpk(exp2f(pv[kt * 4 + 2] - m), exp2f(pv[kt * 4 + 3] - m));
            *(uint2*)&P2[w][tsel][lo][kt * 8 + hi * 2] = wv;
        }
    };

    int kb = half;

    // ==== PHASE 1: both tiles active (kb < nkbF) ====
    for (; kb < nkbF; kb += 2) {
        const int kvb = kb * 64;

        short8v kf0[4], kf1[4];
        #pragma unroll
        for (int kt = 0; kt < 4; ++kt) {
            kf0[kt] = *(const short8v*)(kptr + kt * 1024);
            kf1[kt] = *(const short8v*)(kptr + kt * 1024 + 32);
        }

        f32x4 sB[4], sF[4];
        __builtin_amdgcn_s_setprio(1);
        #pragma unroll
        for (int kt = 0; kt < 4; ++kt) {
            f32x4 a = z;
            a = __builtin_amdgcn_mfma_f32_16x16x32_bf16(kf0[kt], qB0, a, 0, 0, 0);
            a = __builtin_amdgcn_mfma_f32_16x16x32_bf16(kf1[kt], qB1, a, 0, 0, 0);
            sB[kt] = a;
        }
        #pragma unroll
        for (int kt = 0; kt < 4; ++kt) {
            f32x4 a = z;
            a = __builtin_amdgcn_mfma_f32_16x16x32_bf16(kf0[kt], qF0, a, 0, 0, 0);
            a = __builtin_amdgcn_mfma_f32_16x16x32_bf16(kf1[kt], qF1, a, 0, 0, 0);
            sF[kt] = a;
        }
        __builtin_amdgcn_s_setprio(0);

        softmaxTile(sB, mB, oB, laB, false, q0B, kvb, 0);
        softmaxTile(sF, mF, oF, laF, kb == nkbF - 1, q0F, kvb, 1);

        short8v vf0[4], vf1[4];
        #pragma unroll
        for (int dt = 0; dt < 4; ++dt) {
            vf0[dt] = *(const short8v*)(vptr + dt * 128);
            vf1[dt] = *(const short8v*)(vptr + dt * 128 + 2048);
        }

        asm volatile("s_waitcnt lgkmcnt(0)" ::: "memory");
        const short8v paB0 = *(const short8v*)&P2[w][0][lo][hi * 4];
        const short8v paB1 = *(const short8v*)&P2[w][0][lo][16 + hi * 4];
        const short8v paF0 = *(const short8v*)&P2[w][1][lo][hi * 4];
        const short8v paF1 = *(const short8v*)&P2[w][1][lo][16 + hi * 4];

        __builtin_amdgcn_s_setprio(1);
        laB = __builtin_amdgcn_mfma_f32_16x16x32_bf16(paB0, ones, laB, 0, 0, 0);
        laB = __builtin_amdgcn_mfma_f32_16x16x32_bf16(paB1, ones, laB, 0, 0, 0);
        laF = __builtin_amdgcn_mfma_f32_16x16x32_bf16(paF0, ones, laF, 0, 0, 0);
        laF = __builtin_amdgcn_mfma_f32_16x16x32_bf16(paF1, ones, laF, 0, 0, 0);
        #pragma unroll
        for (int dt = 0; dt < 4; ++dt) {
            oB[dt] = __builtin_amdgcn_mfma_f32_16x16x32_bf16(paB0, vf0[dt], oB[dt], 0, 0, 0);
            oB[dt] = __builtin_amdgcn_mfma_f32_16x16x32_bf16(paB1, vf1[dt], oB[dt], 0, 0, 0);
            oF[dt] = __builtin_amdgcn_mfma_f32_16x16x32_bf16(paF0, vf0[dt], oF[dt], 0, 0, 0);
            oF[dt] = __builtin_amdgcn_mfma_f32_16x16x32_bf16(paF1, vf1[dt], oF[dt], 0, 0, 0);
        }
        __builtin_amdgcn_s_setprio(0);

        kptr += 8192;
        vptr += 8192;
    }

    // ==== PHASE 2: B tile only (nkbF <= kb < nkbB) ====
    for (; kb < nkbB; kb += 2) {
        const int kvb = kb * 64;

        short8v kf0[4], kf1[4];
        #pragma unroll
        for (int kt = 0; kt < 4; ++kt) {
            kf0[kt] = *(const short8v*)(kptr + kt * 1024);
            kf1[kt] = *(const short8v*)(kptr + kt * 1024 + 32);
        }

        f32x4 sB[4];
        __builtin_amdgcn_s_setprio(1);
        #pragma unroll
        for (int kt = 0; kt < 4; ++kt) {
            f32x4 a = z;
            a = __builtin_amdgcn_mfma_f32_16x16x32_bf16(kf0[kt], qB0, a, 0, 0, 0);
            a = __builtin_amdgcn_mfma_f32_16x16x32_bf16(kf1[kt], qB1, a, 0, 0, 0);
            sB[kt] = a;
        }
        __builtin_amdgcn_s_setprio(0);

        softmaxTile(sB, mB, oB, laB, kb == nkbB - 1, q0B, kvb, 0);

        short8v vf0[4], vf1[4];
        #pragma unroll
        for (int dt = 0; dt < 4; ++dt) {
            vf0[dt] = *(const short8v*)(vptr + dt * 128);
            vf1[dt] = *(const short8v*)(vptr + dt * 128 + 2048);
        }

        asm volatile("s_waitcnt lgkmcnt(0)" ::: "memory");
        const short8v paB0 = *(const short8v*)&P2[w][0][lo][hi * 4];
        const short8v paB1 = *(const short8v*)&P2[w][0][lo][16 + hi * 4];

        __builtin_amdgcn_s_setprio(1);
        laB = __builtin_amdgcn_mfma_f32_16x16x32_bf16(paB0, ones, laB, 0, 0, 0);
        laB = __builtin_amdgcn_mfma_f32_16x16x32_bf16(paB1, ones, laB, 0, 0, 0);
        #pragma unroll
        for (int dt = 0; dt < 4; ++dt) {
            oB[dt] = __builtin_amdgcn_mfma_f32_16x16x32_bf16(paB0, vf0[dt], oB[dt], 0, 0, 0);
            oB[dt] = __builtin_amdgcn_mfma_f32_16x16x32_bf16(paB1, vf1[dt], oB[dt], 0, 0, 0);
        }
        __builtin_amdgcn_s_setprio(0);

        kptr += 8192;
        vptr += 8192;
    }

    float mBr[4], mFr[4];
    #pragma unroll
    for (int rg = 0; rg < 4; ++rg) {
        mBr[rg] = bperm_f(hi * 4 + rg, mB);
        mFr[rg] = bperm_f(hi * 4 + rg, mF);
    }

#define STORE_TILE(OT, MT, LAT)                                            \
    do {                                                                   \
        f32x4* dst = (f32x4*)&MB[pw][l][0];                                \
        dst[0] = OT[0]; dst[1] = OT[1]; dst[2] = OT[2]; dst[3] = OT[3];    \
        dst[4] = (f32x4){MT[0], MT[1], MT[2], MT[3]};                      \
        dst[5] = LAT;                                                      \
    } while (0)

#define MERGE_TILE(OT, MT, LAT, Q0T)                                       \
    do {                                                                   \
        const f32x4* src = (const f32x4*)&MB[pw][l][0];                    \
        const f32x4 o1_0 = src[0], o1_1 = src[1], o1_2 = src[2], o1_3 = src[3]; \
        const f32x4 m1 = src[4];                                           \
        const f32x4 la1 = src[5];                                          \
        short* Op = Oh + (size_t)(b * S + (Q0T)) * DM + h * DH;            \
        _Pragma("unroll")                                                  \
        for (int rg = 0; rg < 4; ++rg) {                                   \
            const float mst = fmaxf(MT[rg], m1[rg]);                       \
            const float c0 = exp2f(MT[rg] - mst);                          \
            const float c1 = exp2f(m1[rg] - mst);                          \
            const float iv = 1.0f / (LAT[rg] * c0 + la1[rg] * c1);         \
            Op[(size_t)(hi * 4 + rg) * DM +  0 + lo] = f2bf((OT[0][rg] * c0 + o1_0[rg] * c1) * iv); \
            Op[(size_t)(hi * 4 + rg) * DM + 16 + lo] = f2bf((OT[1][rg] * c0 + o1_1[rg] * c1) * iv); \
            Op[(size_t)(hi * 4 + rg) * DM + 32 + lo] = f2bf((OT[2][rg] * c0 + o1_2[rg] * c1) * iv); \
            Op[(size_t)(hi * 4 + rg) * DM + 48 + lo] = f2bf((OT[3][rg] * c0 + o1_3[rg] * c1) * iv); \
        }                                                                  \
    } while (0)

    __syncthreads();
    if (half == 1) STORE_TILE(oB, mBr, laB);
    __syncthreads();
    if (half == 0) MERGE_TILE(oB, mBr, laB, q0B);
    __syncthreads();
    if (half == 1) STORE_TILE(oF, mFr, laF);
    __syncthreads();
    if (half == 0) MERGE_TILE(oF, mFr, laF, q0F);
#undef STORE_TILE
#undef MERGE_TILE
}

// ---------------------------------------------------------------------------
extern "C" void kernel_launch(void* const* d_in, const int* in_sizes, int n_in,
                              void* d_out, int out_size, void* d_ws, size_t ws_size,
                              hipStream_t stream) {
    const float* x  = (const float*)d_in[0];
    const int*  pos = (const int*)d_in[1];
    const float* wq = (const float*)d_in[2];
    const float* wk = (const float*)d_in[3];
    const float* wv = (const float*)d_in[4];
    const float* wo = (const float*)d_in[5];
    float* out = (float*)d_out;

    const int S = in_sizes[1];              // 2048
    const int rows = in_sizes[0] / DM;      // B*S
    const int Bb = rows / S;

    short* xh   = (short*)d_ws;
    short* wqkv = xh + (size_t)rows * DM;
    short* woh  = wqkv + (size_t)QKV * DM;
    short* QKVr = woh + (size_t)DM * DM;
    short* Qh   = QKVr + (size_t)rows * QKV;
    short* Kh   = Qh + (size_t)rows * DM;
    short* Vt   = Kh + (size_t)rows * DM;
    short* Oh   = Vt + (size_t)rows * DM;
    float2* cst = (float2*)(Oh + (size_t)rows * DM);

    const int nx = rows * DM;
    const int nw = DM * DM;
    const int nprep = (nx + 4 * nw) / 4 + S * 32;
    prep<<<(nprep + 255) / 256, 256, 0, stream>>>(
        x, wq, wk, wv, wo, pos, xh, wqkv, woh, cst, nx, nw, S);

    gemm_bt_mfma<1><<<dim3((QKV / 128) * (rows / 128)), 256, 0, stream>>>(
        xh, wqkv, QKVr, rows, QKV, DM, rows / 128);

    const int ropeBlk = (rows * DM + 255) / 256;
    const int vtBlk = (S / 64) * (Bb * NH);
    rope_vt<<<ropeBlk + vtBlk, 256, 0, stream>>>(
        QKVr, cst, Qh, Kh, Vt, S, rows, ropeBlk);

    const int Tq = S / 16;
    const int bpb = Tq / 4;
    const int nbh = Bb * NH;
    attn_mfma<<<dim3(nbh * bpb), 256, 0, stream>>>(Qh, Kh, Vt, Oh, S, bpb);

    gemm_bt_mfma<0><<<dim3((DM / 128) * (rows / 128)), 256, 0, stream>>>(
        Oh, woh, out, rows, DM, DM, rows / 128);
}

// Round 21
// 157.186 us; speedup vs baseline: 1.0463x; 1.0397x over previous
//
#include <hip/hip_runtime.h>
#include <hip/hip_bf16.h>
#include <math.h>

static constexpr int DM = 1024;   // d_model
static constexpr int NH = 16;     // heads
static constexpr int DH = 64;     // head dim
static constexpr int QKV = 3 * DM;

typedef __attribute__((ext_vector_type(8))) short short8v;  // 8 bf16 = 4 VGPR
typedef __attribute__((ext_vector_type(4))) float f32x4;

__device__ inline short f2bf(float x) {
    __hip_bfloat16 h = __float2bfloat16(x);
    return *reinterpret_cast<short*>(&h);
}

// pack two f32 -> u32 of 2 bf16 (lo word = first arg), RNE
__device__ inline unsigned cvtpk(float a, float b) {
    unsigned r;
    asm("v_cvt_pk_bf16_f32 %0, %1, %2" : "=v"(r) : "v"(a), "v"(b));
    return r;
}

// pull f32 from srclane (0..63)
__device__ inline float bperm_f(int srclane, float v) {
    return __int_as_float(
        __builtin_amdgcn_ds_bpermute(srclane << 2, __float_as_int(v)));
}

// async global->LDS, 16B per lane.
__device__ inline void gload16(const void* g, void* l) {
    __builtin_amdgcn_global_load_lds(
        (const __attribute__((address_space(1))) unsigned int*)g,
        (__attribute__((address_space(3))) unsigned int*)l, 16, 0, 0);
}

// ---------------------------------------------------------------------------
// prep = fused {fp32->bf16 convert of all five inputs} U {cos/sin table}.
// ---------------------------------------------------------------------------
__global__ __launch_bounds__(256)
void prep(const float* __restrict__ x,  const float* __restrict__ wq,
          const float* __restrict__ wk, const float* __restrict__ wv,
          const float* __restrict__ wo, const int* __restrict__ pos,
          short* __restrict__ xh, short* __restrict__ wqkv,
          short* __restrict__ woh, float2* __restrict__ cst,
          int nx, int nw, int S) {
    const int t = blockIdx.x * 256 + threadIdx.x;
    const int nconv = (nx + 4 * nw) / 4;
    if (t < nconv) {
        const int i = t * 4;
        const float* src;
        short* dst;
        int off;
        if (i < nx)                { src = x;  dst = xh;            off = i; }
        else if (i < nx + nw)      { src = wq; dst = wqkv;          off = i - nx; }
        else if (i < nx + 2 * nw)  { src = wk; dst = wqkv + nw;     off = i - nx - nw; }
        else if (i < nx + 3 * nw)  { src = wv; dst = wqkv + 2 * nw; off = i - nx - 2 * nw; }
        else                       { src = wo; dst = woh;           off = i - nx - 3 * nw; }
        const float4 v = *(const float4*)(src + off);
        short4 o;
        o.x = f2bf(v.x); o.y = f2bf(v.y); o.z = f2bf(v.z); o.w = f2bf(v.w);
        *(short4*)(dst + off) = o;
    } else {
        const int j = t - nconv;
        if (j >= S * 32) return;
        const int s = j >> 5, k = j & 31;
        const float ang = (float)pos[s] * powf(10000.0f, -(float)k * (1.0f / 32.0f));
        cst[j] = make_float2(cosf(ang), sinf(ang));
    }
}

// ---------------------------------------------------------------------------
// bf16 MFMA GEMM, m97 structure + XCD-aware block swizzle (passing).
// Used for the QKV projection (bf16 out).
// ---------------------------------------------------------------------------
template <int BF16OUT>
__global__ __launch_bounds__(256)
void gemm_bt_mfma(const short* __restrict__ A, const short* __restrict__ B,
                  void* __restrict__ Cv, int M, int N, int K, int gy) {
    __shared__ __align__(16) short As[128 * 32];
    __shared__ __align__(16) short Bs[128 * 32];
    const int tid = threadIdx.x;
    const int w = tid >> 6, l = tid & 63;
    const int lo = l & 15, hi = l >> 4;
    const int wr = w >> 1, wc = w & 1;

    const int flat = blockIdx.x;
    const int cpx = gridDim.x >> 3;
    const int s = (flat & 7) * cpx + (flat >> 3);
    const int by = s % gy, bx = s / gy;
    const size_t m0 = (size_t)by * 128;
    const size_t n0 = (size_t)bx * 128;

    const int cr = (w * 2) * 16 + (l >> 2);
    const int cc = (l & 3) * 8;
    const short* Ag0 = A + (m0 + cr) * K + cc;
    const short* Ag1 = Ag0 + (size_t)16 * K;
    const short* Bg0 = B + (n0 + cr) * K + cc;
    const short* Bg1 = Bg0 + (size_t)16 * K;
    short* As0 = As + (w * 2) * 512;
    short* As1 = As0 + 512;
    short* Bs0 = Bs + (w * 2) * 512;
    short* Bs1 = Bs0 + 512;

    f32x4 acc[4][4];
    #pragma unroll
    for (int mi = 0; mi < 4; ++mi)
        #pragma unroll
        for (int nj = 0; nj < 4; ++nj)
            acc[mi][nj] = (f32x4){0.f, 0.f, 0.f, 0.f};

    const int aoff = (wr * 64 + lo) * 32 + hi * 8;
    const int boff = (wc * 64 + lo) * 32 + hi * 8;

    for (int k0 = 0; k0 < K; k0 += 32) {
        __syncthreads();
        gload16(Ag0 + k0, As0);
        gload16(Ag1 + k0, As1);
        gload16(Bg0 + k0, Bs0);
        gload16(Bg1 + k0, Bs1);
        __syncthreads();
        short8v af[4], bf[4];
        #pragma unroll
        for (int mi = 0; mi < 4; ++mi)
            af[mi] = *(const short8v*)&As[aoff + mi * 16 * 32];
        #pragma unroll
        for (int nj = 0; nj < 4; ++nj)
            bf[nj] = *(const short8v*)&Bs[boff + nj * 16 * 32];
        #pragma unroll
        for (int mi = 0; mi < 4; ++mi)
            #pragma unroll
            for (int nj = 0; nj < 4; ++nj)
                acc[mi][nj] = __builtin_amdgcn_mfma_f32_16x16x32_bf16(
                    af[mi], bf[nj], acc[mi][nj], 0, 0, 0);
    }

    const size_t mbase = m0 + wr * 64 + hi * 4;
    const size_t nbase = n0 + wc * 64 + lo;
    #pragma unroll
    for (int mi = 0; mi < 4; ++mi)
        #pragma unroll
        for (int nj = 0; nj < 4; ++nj)
            #pragma unroll
            for (int rg = 0; rg < 4; ++rg) {
                const size_t m = mbase + mi * 16 + rg;
                const size_t n = nbase + nj * 16;
                if (BF16OUT)
                    ((short*)Cv)[m * N + n] = f2bf(acc[mi][nj][rg]);
                else
                    ((float*)Cv)[m * N + n] = acc[mi][nj][rg];
            }
}

// ---------------------------------------------------------------------------
// BM=64 x BN=128 variant for the out-projection (N=1024 -> only 256 blocks
// at 128x128 = 1 block/CU = exposed barrier drains). 512 blocks = 2/CU.
// Same m97 pattern: wave w stages A-chunk w (16 rows) + B-chunks 2w,2w+1;
// wave (wr,wc) computes 32x64 output quadrant, acc[2][4]. fp32 out.
// ---------------------------------------------------------------------------
__global__ __launch_bounds__(256)
void gemm_bt_mfma64(const short* __restrict__ A, const short* __restrict__ B,
                    float* __restrict__ C, int M, int N, int K, int gy) {
    __shared__ __align__(16) short As[64 * 32];     // 4 KB
    __shared__ __align__(16) short Bs[128 * 32];    // 8 KB
    const int tid = threadIdx.x;
    const int w = tid >> 6, l = tid & 63;
    const int lo = l & 15, hi = l >> 4;
    const int wr = w >> 1, wc = w & 1;

    const int flat = blockIdx.x;
    const int cpx = gridDim.x >> 3;
    const int s = (flat & 7) * cpx + (flat >> 3);
    const int by = s % gy, bx = s / gy;
    const size_t m0 = (size_t)by * 64;
    const size_t n0 = (size_t)bx * 128;

    const int crr = l >> 2;              // row within 16-row chunk
    const int cc = (l & 3) * 8;
    const short* Ag  = A + (m0 + w * 16 + crr) * K + cc;
    const short* Bg0 = B + (n0 + (2 * w) * 16 + crr) * K + cc;
    const short* Bg1 = Bg0 + (size_t)16 * K;
    short* As0 = As + w * 512;
    short* Bs0 = Bs + (2 * w) * 512;
    short* Bs1 = Bs0 + 512;

    f32x4 acc[2][4];
    #pragma unroll
    for (int mi = 0; mi < 2; ++mi)
        #pragma unroll
        for (int nj = 0; nj < 4; ++nj)
            acc[mi][nj] = (f32x4){0.f, 0.f, 0.f, 0.f};

    const int aoff = (wr * 32 + lo) * 32 + hi * 8;
    const int boff = (wc * 64 + lo) * 32 + hi * 8;

    for (int k0 = 0; k0 < K; k0 += 32) {
        __syncthreads();
        gload16(Ag + k0, As0);
        gload16(Bg0 + k0, Bs0);
        gload16(Bg1 + k0, Bs1);
        __syncthreads();
        short8v af[2], bf[4];
        #pragma unroll
        for (int mi = 0; mi < 2; ++mi)
            af[mi] = *(const short8v*)&As[aoff + mi * 16 * 32];
        #pragma unroll
        for (int nj = 0; nj < 4; ++nj)
            bf[nj] = *(const short8v*)&Bs[boff + nj * 16 * 32];
        #pragma unroll
        for (int mi = 0; mi < 2; ++mi)
            #pragma unroll
            for (int nj = 0; nj < 4; ++nj)
                acc[mi][nj] = __builtin_amdgcn_mfma_f32_16x16x32_bf16(
                    af[mi], bf[nj], acc[mi][nj], 0, 0, 0);
    }

    const size_t mbase = m0 + wr * 32 + hi * 4;
    const size_t nbase = n0 + wc * 64 + lo;
    #pragma unroll
    for (int mi = 0; mi < 2; ++mi)
        #pragma unroll
        for (int nj = 0; nj < 4; ++nj)
            #pragma unroll
            for (int rg = 0; rg < 4; ++rg)
                C[(mbase + mi * 16 + rg) * N + nbase + nj * 16] =
                    acc[mi][nj][rg];
}

// ---------------------------------------------------------------------------
// rope_vt = fused {RoPE on Q/K} U {V -> blocked-transposed Vt2}. (passing)
// ---------------------------------------------------------------------------
__global__ __launch_bounds__(256)
void rope_vt(const short* __restrict__ QKVr, const float2* __restrict__ cst,
             short* __restrict__ Qh, short* __restrict__ Kh,
             short* __restrict__ Vt, int S, int rows, int ropeBlk) {
    __shared__ __align__(16) short T[64][72];
    const int tid = threadIdx.x;

    if ((int)blockIdx.x < ropeBlk) {
        int idx = blockIdx.x * 256 + tid;
        const int per = rows * (DM / 2);
        bool isK = false;
        if (idx >= per) { idx -= per; isK = true; }
        if (idx >= per) return;
        const int row = idx >> 9;
        const int rem = idx & 511;
        const int h = rem >> 5, k = rem & 31;
        const int b = row / S, sr = row - b * S;
        const unsigned pin = *(const unsigned*)(QKVr + (size_t)row * QKV +
                                                (isK ? DM : 0) + h * DH + 2 * k);
        const float x0 = __uint_as_float(pin << 16);
        const float x1 = __uint_as_float(pin & 0xffff0000u);
        const float2 cs = cst[sr * 32 + k];
        float y0 = cs.x * x0 - cs.y * x1;
        float y1 = cs.y * x0 + cs.x * x1;
        if (!isK) {
            const float qs = 0.125f * 1.4426950408889634f;
            y0 *= qs; y1 *= qs;
        }
        short* dst = (isK ? Kh : Qh) + ((size_t)(b * NH + h) * S + sr) * DH + 2 * k;
        *(unsigned*)dst = ((unsigned)(unsigned short)f2bf(y1) << 16)
                        | (unsigned short)f2bf(y0);
    } else {
        const int vb = blockIdx.x - ropeBlk;
        const int nsx = S >> 6;
        const int sx = vb % nsx, bh = vb / nsx;
        const int b = bh / NH, h = bh - b * NH;
        const int s0 = sx * 64;
        const int r = tid >> 2, seg = (tid & 3) * 16;
        const short* src = QKVr + (size_t)(b * S + s0 + r) * QKV + 2 * DM + h * DH + seg;
        const short8v a0 = *(const short8v*)(src);
        const short8v a1 = *(const short8v*)(src + 8);
        #pragma unroll
        for (int j = 0; j < 8; ++j) T[seg + j][r] = a0[j];
        #pragma unroll
        for (int j = 0; j < 8; ++j) T[seg + 8 + j][r] = a1[j];
        __syncthreads();
        const int d = tid >> 2, q = tid & 3;
        short* Vp2 = Vt + (size_t)bh * DH * S;
        #pragma unroll
        for (int j = 0; j < 2; ++j) {
            const int sbl = q * 2 + j;
            const uint4 v = *(const uint4*)&T[d][sbl * 8];
            *(uint4*)&Vp2[(((size_t)(s0 >> 3) + sbl) * 64 + d) * 8] = v;
        }
    }
}

// ---------------------------------------------------------------------------
// MFMA flash attention (R20, unchanged, passing): swapped QK^T in-register
// softmax (exp2 domain), Vt2-blocked V loads, KV-split, XCD swizzle,
// defer-max, MFMA row-sum, setprio MFMA clusters, joint/solo phase split,
// spill-free combine.
// ---------------------------------------------------------------------------
__global__ __launch_bounds__(256)
void attn_mfma(const short* __restrict__ Qh, const short* __restrict__ Kh,
               const short* __restrict__ Vt, short* __restrict__ Oh,
               int S, int bpb) {
    __shared__ __align__(16) unsigned P2[4][2][16][36];   // 18432 B
    __shared__ __align__(16) float MB[2][64][24];         // 12288 B

    const int tid = threadIdx.x;
    const int w = tid >> 6, l = tid & 63;
    const int pw = w >> 1, half = w & 1;
    const int lo = l & 15, hi = l >> 4;
    const int T = S >> 4;

    const int flat = blockIdx.x;
    const int bh3 = flat & 7;
    const int r = flat >> 3;
    const int grp = r / bpb, blk = r - grp * bpb;
    const int bh = grp * 8 + bh3;
    const int b = bh >> 4, h = bh & 15;          // NH = 16
    const int p = blk * 2 + pw;

    const int q0B = (T - 1 - p) << 4;
    const int q0F = p << 4;
    const int nkbB = (q0B + 79) >> 6;
    const int nkbF = (q0F + 79) >> 6;

    const short* Qp = Qh + (size_t)bh * S * DH;

    const short8v qB0 = *(const short8v*)(Qp + (size_t)(q0B + lo) * DH + hi * 8);
    const short8v qB1 = *(const short8v*)(Qp + (size_t)(q0B + lo) * DH + 32 + hi * 8);
    const short8v qF0 = *(const short8v*)(Qp + (size_t)(q0F + lo) * DH + hi * 8);
    const short8v qF1 = *(const short8v*)(Qp + (size_t)(q0F + lo) * DH + 32 + hi * 8);

    const short* kptr = Kh + (size_t)bh * S * DH
                      + (size_t)(half * 64 + lo) * DH + hi * 8;
    const short* vptr = Vt + (size_t)bh * DH * S
                      + (size_t)(half * 8 + hi) * 512 + lo * 8;

    short8v ones;
    #pragma unroll
    for (int i = 0; i < 8; ++i) ones[i] = (short)0x3F80;   // bf16 1.0

    f32x4 oB[4], oF[4];
    f32x4 laB = (f32x4){0.f, 0.f, 0.f, 0.f};
    f32x4 laF = (f32x4){0.f, 0.f, 0.f, 0.f};
    float mB = -INFINITY, mF = -INFINITY;
    #pragma unroll
    for (int i = 0; i < 4; ++i) {
        oB[i] = (f32x4){0.f, 0.f, 0.f, 0.f};
        oF[i] = (f32x4){0.f, 0.f, 0.f, 0.f};
    }
    const f32x4 z = (f32x4){0.f, 0.f, 0.f, 0.f};

    auto softmaxTile = [&](const f32x4 (&s)[4], float& m, f32x4 (&o)[4],
                           f32x4& la, bool masked, int q0, int kvb, int tsel) {
        float pv[16];
        float bm = -INFINITY;
        const int lim = q0 + lo - kvb;
        #pragma unroll
        for (int kt = 0; kt < 4; ++kt)
            #pragma unroll
            for (int rg = 0; rg < 4; ++rg) {
                float v = s[kt][rg];
                if (masked && (kt * 16 + hi * 4 + rg > lim)) v = -INFINITY;
                pv[kt * 4 + rg] = v;
                bm = fmaxf(bm, v);
            }
        bm = fmaxf(bm, __shfl_xor(bm, 16));
        bm = fmaxf(bm, __shfl_xor(bm, 32));
        if (__any(bm > m + 8.0f)) {
            const float mn = fmaxf(m, bm);
            const float c = exp2f(m - mn);
            m = mn;
            #pragma unroll
            for (int rg = 0; rg < 4; ++rg) {
                const float cr = bperm_f(hi * 4 + rg, c);
                la[rg] *= cr;
                #pragma unroll
                for (int dt = 0; dt < 4; ++dt) o[dt][rg] *= cr;
            }
        }
        #pragma unroll
        for (int kt = 0; kt < 4; ++kt) {
            uint2 wv;
            wv.x = cvtpk(exp2f(pv[kt * 4 + 0] - m), exp2f(pv[kt * 4 + 1] - m));
            wv.y = cvtpk(exp2f(pv[kt * 4 + 2] - m), exp2f(pv[kt * 4 + 3] - m));
            *(uint2*)&P2[w][tsel][lo][kt * 8 + hi * 2] = wv;
        }
    };

    int kb = half;

    // ==== PHASE 1: both tiles active (kb < nkbF) ====
    for (; kb < nkbF; kb += 2) {
        const int kvb = kb * 64;

        short8v kf0[4], kf1[4];
        #pragma unroll
        for (int kt = 0; kt < 4; ++kt) {
            kf0[kt] = *(const short8v*)(kptr + kt * 1024);
            kf1[kt] = *(const short8v*)(kptr + kt * 1024 + 32);
        }

        f32x4 sB[4], sF[4];
        __builtin_amdgcn_s_setprio(1);
        #pragma unroll
        for (int kt = 0; kt < 4; ++kt) {
            f32x4 a = z;
            a = __builtin_amdgcn_mfma_f32_16x16x32_bf16(kf0[kt], qB0, a, 0, 0, 0);
            a = __builtin_amdgcn_mfma_f32_16x16x32_bf16(kf1[kt], qB1, a, 0, 0, 0);
            sB[kt] = a;
        }
        #pragma unroll
        for (int kt = 0; kt < 4; ++kt) {
            f32x4 a = z;
            a = __builtin_amdgcn_mfma_f32_16x16x32_bf16(kf0[kt], qF0, a, 0, 0, 0);
            a = __builtin_amdgcn_mfma_f32_16x16x32_bf16(kf1[kt], qF1, a, 0, 0, 0);
            sF[kt] = a;
        }
        __builtin_amdgcn_s_setprio(0);

        softmaxTile(sB, mB, oB, laB, false, q0B, kvb, 0);
        softmaxTile(sF, mF, oF, laF, kb == nkbF - 1, q0F, kvb, 1);

        short8v vf0[4], vf1[4];
        #pragma unroll
        for (int dt = 0; dt < 4; ++dt) {
            vf0[dt] = *(const short8v*)(vptr + dt * 128);
            vf1[dt] = *(const short8v*)(vptr + dt * 128 + 2048);
        }

        asm volatile("s_waitcnt lgkmcnt(0)" ::: "memory");
        const short8v paB0 = *(const short8v*)&P2[w][0][lo][hi * 4];
        const short8v paB1 = *(const short8v*)&P2[w][0][lo][16 + hi * 4];
        const short8v paF0 = *(const short8v*)&P2[w][1][lo][hi * 4];
        const short8v paF1 = *(const short8v*)&P2[w][1][lo][16 + hi * 4];

        __builtin_amdgcn_s_setprio(1);
        laB = __builtin_amdgcn_mfma_f32_16x16x32_bf16(paB0, ones, laB, 0, 0, 0);
        laB = __builtin_amdgcn_mfma_f32_16x16x32_bf16(paB1, ones, laB, 0, 0, 0);
        laF = __builtin_amdgcn_mfma_f32_16x16x32_bf16(paF0, ones, laF, 0, 0, 0);
        laF = __builtin_amdgcn_mfma_f32_16x16x32_bf16(paF1, ones, laF, 0, 0, 0);
        #pragma unroll
        for (int dt = 0; dt < 4; ++dt) {
            oB[dt] = __builtin_amdgcn_mfma_f32_16x16x32_bf16(paB0, vf0[dt], oB[dt], 0, 0, 0);
            oB[dt] = __builtin_amdgcn_mfma_f32_16x16x32_bf16(paB1, vf1[dt], oB[dt], 0, 0, 0);
            oF[dt] = __builtin_amdgcn_mfma_f32_16x16x32_bf16(paF0, vf0[dt], oF[dt], 0, 0, 0);
            oF[dt] = __builtin_amdgcn_mfma_f32_16x16x32_bf16(paF1, vf1[dt], oF[dt], 0, 0, 0);
        }
        __builtin_amdgcn_s_setprio(0);

        kptr += 8192;
        vptr += 8192;
    }

    // ==== PHASE 2: B tile only (nkbF <= kb < nkbB) ====
    for (; kb < nkbB; kb += 2) {
        const int kvb = kb * 64;

        short8v kf0[4], kf1[4];
        #pragma unroll
        for (int kt = 0; kt < 4; ++kt) {
            kf0[kt] = *(const short8v*)(kptr + kt * 1024);
            kf1[kt] = *(const short8v*)(kptr + kt * 1024 + 32);
        }

        f32x4 sB[4];
        __builtin_amdgcn_s_setprio(1);
        #pragma unroll
        for (int kt = 0; kt < 4; ++kt) {
            f32x4 a = z;
            a = __builtin_amdgcn_mfma_f32_16x16x32_bf16(kf0[kt], qB0, a, 0, 0, 0);
            a = __builtin_amdgcn_mfma_f32_16x16x32_bf16(kf1[kt], qB1, a, 0, 0, 0);
            sB[kt] = a;
        }
        __builtin_amdgcn_s_setprio(0);

        softmaxTile(sB, mB, oB, laB, kb == nkbB - 1, q0B, kvb, 0);

        short8v vf0[4], vf1[4];
        #pragma unroll
        for (int dt = 0; dt < 4; ++dt) {
            vf0[dt] = *(const short8v*)(vptr + dt * 128);
            vf1[dt] = *(const short8v*)(vptr + dt * 128 + 2048);
        }

        asm volatile("s_waitcnt lgkmcnt(0)" ::: "memory");
        const short8v paB0 = *(const short8v*)&P2[w][0][lo][hi * 4];
        const short8v paB1 = *(const short8v*)&P2[w][0][lo][16 + hi * 4];

        __builtin_amdgcn_s_setprio(1);
        laB = __builtin_amdgcn_mfma_f32_16x16x32_bf16(paB0, ones, laB, 0, 0, 0);
        laB = __builtin_amdgcn_mfma_f32_16x16x32_bf16(paB1, ones, laB, 0, 0, 0);
        #pragma unroll
        for (int dt = 0; dt < 4; ++dt) {
            oB[dt] = __builtin_amdgcn_mfma_f32_16x16x32_bf16(paB0, vf0[dt], oB[dt], 0, 0, 0);
            oB[dt] = __builtin_amdgcn_mfma_f32_16x16x32_bf16(paB1, vf1[dt], oB[dt], 0, 0, 0);
        }
        __builtin_amdgcn_s_setprio(0);

        kptr += 8192;
        vptr += 8192;
    }

    float mBr[4], mFr[4];
    #pragma unroll
    for (int rg = 0; rg < 4; ++rg) {
        mBr[rg] = bperm_f(hi * 4 + rg, mB);
        mFr[rg] = bperm_f(hi * 4 + rg, mF);
    }

#define STORE_TILE(OT, MT, LAT)                                            \
    do {                                                                   \
        f32x4* dst = (f32x4*)&MB[pw][l][0];                                \
        dst[0] = OT[0]; dst[1] = OT[1]; dst[2] = OT[2]; dst[3] = OT[3];    \
        dst[4] = (f32x4){MT[0], MT[1], MT[2], MT[3]};                      \
        dst[5] = LAT;                                                      \
    } while (0)

#define MERGE_TILE(OT, MT, LAT, Q0T)                                       \
    do {                                                                   \
        const f32x4* src = (const f32x4*)&MB[pw][l][0];                    \
        const f32x4 o1_0 = src[0], o1_1 = src[1], o1_2 = src[2], o1_3 = src[3]; \
        const f32x4 m1 = src[4];                                           \
        const f32x4 la1 = src[5];                                          \
        short* Op = Oh + (size_t)(b * S + (Q0T)) * DM + h * DH;            \
        _Pragma("unroll")                                                  \
        for (int rg = 0; rg < 4; ++rg) {                                   \
            const float mst = fmaxf(MT[rg], m1[rg]);                       \
            const float c0 = exp2f(MT[rg] - mst);                          \
            const float c1 = exp2f(m1[rg] - mst);                          \
            const float iv = 1.0f / (LAT[rg] * c0 + la1[rg] * c1);         \
            Op[(size_t)(hi * 4 + rg) * DM +  0 + lo] = f2bf((OT[0][rg] * c0 + o1_0[rg] * c1) * iv); \
            Op[(size_t)(hi * 4 + rg) * DM + 16 + lo] = f2bf((OT[1][rg] * c0 + o1_1[rg] * c1) * iv); \
            Op[(size_t)(hi * 4 + rg) * DM + 32 + lo] = f2bf((OT[2][rg] * c0 + o1_2[rg] * c1) * iv); \
            Op[(size_t)(hi * 4 + rg) * DM + 48 + lo] = f2bf((OT[3][rg] * c0 + o1_3[rg] * c1) * iv); \
        }                                                                  \
    } while (0)

    __syncthreads();
    if (half == 1) STORE_TILE(oB, mBr, laB);
    __syncthreads();
    if (half == 0) MERGE_TILE(oB, mBr, laB, q0B);
    __syncthreads();
    if (half == 1) STORE_TILE(oF, mFr, laF);
    __syncthreads();
    if (half == 0) MERGE_TILE(oF, mFr, laF, q0F);
#undef STORE_TILE
#undef MERGE_TILE
}

// ---------------------------------------------------------------------------
extern "C" void kernel_launch(void* const* d_in, const int* in_sizes, int n_in,
                              void* d_out, int out_size, void* d_ws, size_t ws_size,
                              hipStream_t stream) {
    const float* x  = (const float*)d_in[0];
    const int*  pos = (const int*)d_in[1];
    const float* wq = (const float*)d_in[2];
    const float* wk = (const float*)d_in[3];
    const float* wv = (const float*)d_in[4];
    const float* wo = (const float*)d_in[5];
    float* out = (float*)d_out;

    const int S = in_sizes[1];              // 2048
    const int rows = in_sizes[0] / DM;      // B*S
    const int Bb = rows / S;

    short* xh   = (short*)d_ws;
    short* wqkv = xh + (size_t)rows * DM;
    short* woh  = wqkv + (size_t)QKV * DM;
    short* QKVr = woh + (size_t)DM * DM;
    short* Qh   = QKVr + (size_t)rows * QKV;
    short* Kh   = Qh + (size_t)rows * DM;
    short* Vt   = Kh + (size_t)rows * DM;
    short* Oh   = Vt + (size_t)rows * DM;
    float2* cst = (float2*)(Oh + (size_t)rows * DM);

    const int nx = rows * DM;
    const int nw = DM * DM;
    const int nprep = (nx + 4 * nw) / 4 + S * 32;
    prep<<<(nprep + 255) / 256, 256, 0, stream>>>(
        x, wq, wk, wv, wo, pos, xh, wqkv, woh, cst, nx, nw, S);

    gemm_bt_mfma<1><<<dim3((QKV / 128) * (rows / 128)), 256, 0, stream>>>(
        xh, wqkv, QKVr, rows, QKV, DM, rows / 128);

    const int ropeBlk = (rows * DM + 255) / 256;
    const int vtBlk = (S / 64) * (Bb * NH);
    rope_vt<<<ropeBlk + vtBlk, 256, 0, stream>>>(
        QKVr, cst, Qh, Kh, Vt, S, rows, ropeBlk);

    const int Tq = S / 16;
    const int bpb = Tq / 4;
    const int nbh = Bb * NH;
    attn_mfma<<<dim3(nbh * bpb), 256, 0, stream>>>(Qh, Kh, Vt, Oh, S, bpb);

    // out projection: BM=64 variant -> 512 blocks = 2/CU (was 256 = 1/CU).
    gemm_bt_mfma64<<<dim3((DM / 128) * (rows / 64)), 256, 0, stream>>>(
        Oh, woh, out, rows, DM, DM, rows / 64);
}

// Round 22
// 156.570 us; speedup vs baseline: 1.0504x; 1.0039x over previous
//
#include <hip/hip_runtime.h>
#include <hip/hip_bf16.h>
#include <math.h>

static constexpr int DM = 1024;   // d_model
static constexpr int NH = 16;     // heads
static constexpr int DH = 64;     // head dim
static constexpr int QKV = 3 * DM;

typedef __attribute__((ext_vector_type(8))) short short8v;  // 8 bf16 = 4 VGPR
typedef __attribute__((ext_vector_type(4))) float f32x4;

__device__ inline short f2bf(float x) {
    __hip_bfloat16 h = __float2bfloat16(x);
    return *reinterpret_cast<short*>(&h);
}

// pack two f32 -> u32 of 2 bf16 (lo word = first arg), RNE
__device__ inline unsigned cvtpk(float a, float b) {
    unsigned r;
    asm("v_cvt_pk_bf16_f32 %0, %1, %2" : "=v"(r) : "v"(a), "v"(b));
    return r;
}

// pull f32 from srclane (0..63)
__device__ inline float bperm_f(int srclane, float v) {
    return __int_as_float(
        __builtin_amdgcn_ds_bpermute(srclane << 2, __float_as_int(v)));
}

// async global->LDS, 16B per lane.
__device__ inline void gload16(const void* g, void* l) {
    __builtin_amdgcn_global_load_lds(
        (const __attribute__((address_space(1))) unsigned int*)g,
        (__attribute__((address_space(3))) unsigned int*)l, 16, 0, 0);
}

// ---------------------------------------------------------------------------
// prep = fused {fp32->bf16 convert of all five inputs} U {cos/sin table}.
// ---------------------------------------------------------------------------
__global__ __launch_bounds__(256)
void prep(const float* __restrict__ x,  const float* __restrict__ wq,
          const float* __restrict__ wk, const float* __restrict__ wv,
          const float* __restrict__ wo, const int* __restrict__ pos,
          short* __restrict__ xh, short* __restrict__ wqkv,
          short* __restrict__ woh, float2* __restrict__ cst,
          int nx, int nw, int S) {
    const int t = blockIdx.x * 256 + threadIdx.x;
    const int nconv = (nx + 4 * nw) / 4;
    if (t < nconv) {
        const int i = t * 4;
        const float* src;
        short* dst;
        int off;
        if (i < nx)                { src = x;  dst = xh;            off = i; }
        else if (i < nx + nw)      { src = wq; dst = wqkv;          off = i - nx; }
        else if (i < nx + 2 * nw)  { src = wk; dst = wqkv + nw;     off = i - nx - nw; }
        else if (i < nx + 3 * nw)  { src = wv; dst = wqkv + 2 * nw; off = i - nx - 2 * nw; }
        else                       { src = wo; dst = woh;           off = i - nx - 3 * nw; }
        const float4 v = *(const float4*)(src + off);
        short4 o;
        o.x = f2bf(v.x); o.y = f2bf(v.y); o.z = f2bf(v.z); o.w = f2bf(v.w);
        *(short4*)(dst + off) = o;
    } else {
        const int j = t - nconv;
        if (j >= S * 32) return;
        const int s = j >> 5, k = j & 31;
        const float ang = (float)pos[s] * powf(10000.0f, -(float)k * (1.0f / 32.0f));
        cst[j] = make_float2(cosf(ang), sinf(ang));
    }
}

// ---------------------------------------------------------------------------
// bf16 MFMA GEMM, m97 structure + XCD-aware block swizzle (passing).
// Used for the QKV projection (bf16 out).
// ---------------------------------------------------------------------------
template <int BF16OUT>
__global__ __launch_bounds__(256)
void gemm_bt_mfma(const short* __restrict__ A, const short* __restrict__ B,
                  void* __restrict__ Cv, int M, int N, int K, int gy) {
    __shared__ __align__(16) short As[128 * 32];
    __shared__ __align__(16) short Bs[128 * 32];
    const int tid = threadIdx.x;
    const int w = tid >> 6, l = tid & 63;
    const int lo = l & 15, hi = l >> 4;
    const int wr = w >> 1, wc = w & 1;

    const int flat = blockIdx.x;
    const int cpx = gridDim.x >> 3;
    const int s = (flat & 7) * cpx + (flat >> 3);
    const int by = s % gy, bx = s / gy;
    const size_t m0 = (size_t)by * 128;
    const size_t n0 = (size_t)bx * 128;

    const int cr = (w * 2) * 16 + (l >> 2);
    const int cc = (l & 3) * 8;
    const short* Ag0 = A + (m0 + cr) * K + cc;
    const short* Ag1 = Ag0 + (size_t)16 * K;
    const short* Bg0 = B + (n0 + cr) * K + cc;
    const short* Bg1 = Bg0 + (size_t)16 * K;
    short* As0 = As + (w * 2) * 512;
    short* As1 = As0 + 512;
    short* Bs0 = Bs + (w * 2) * 512;
    short* Bs1 = Bs0 + 512;

    f32x4 acc[4][4];
    #pragma unroll
    for (int mi = 0; mi < 4; ++mi)
        #pragma unroll
        for (int nj = 0; nj < 4; ++nj)
            acc[mi][nj] = (f32x4){0.f, 0.f, 0.f, 0.f};

    const int aoff = (wr * 64 + lo) * 32 + hi * 8;
    const int boff = (wc * 64 + lo) * 32 + hi * 8;

    for (int k0 = 0; k0 < K; k0 += 32) {
        __syncthreads();
        gload16(Ag0 + k0, As0);
        gload16(Ag1 + k0, As1);
        gload16(Bg0 + k0, Bs0);
        gload16(Bg1 + k0, Bs1);
        __syncthreads();
        short8v af[4], bf[4];
        #pragma unroll
        for (int mi = 0; mi < 4; ++mi)
            af[mi] = *(const short8v*)&As[aoff + mi * 16 * 32];
        #pragma unroll
        for (int nj = 0; nj < 4; ++nj)
            bf[nj] = *(const short8v*)&Bs[boff + nj * 16 * 32];
        #pragma unroll
        for (int mi = 0; mi < 4; ++mi)
            #pragma unroll
            for (int nj = 0; nj < 4; ++nj)
                acc[mi][nj] = __builtin_amdgcn_mfma_f32_16x16x32_bf16(
                    af[mi], bf[nj], acc[mi][nj], 0, 0, 0);
    }

    const size_t mbase = m0 + wr * 64 + hi * 4;
    const size_t nbase = n0 + wc * 64 + lo;
    #pragma unroll
    for (int mi = 0; mi < 4; ++mi)
        #pragma unroll
        for (int nj = 0; nj < 4; ++nj)
            #pragma unroll
            for (int rg = 0; rg < 4; ++rg) {
                const size_t m = mbase + mi * 16 + rg;
                const size_t n = nbase + nj * 16;
                if (BF16OUT)
                    ((short*)Cv)[m * N + n] = f2bf(acc[mi][nj][rg]);
                else
                    ((float*)Cv)[m * N + n] = acc[mi][nj][rg];
            }
}

// ---------------------------------------------------------------------------
// BM=64 x BN=128 variant for the out-projection (R21, passing): 512 blocks
// = 2 blocks/CU (vs 1/CU at 128x128) -> barrier drains overlap.
// ---------------------------------------------------------------------------
__global__ __launch_bounds__(256)
void gemm_bt_mfma64(const short* __restrict__ A, const short* __restrict__ B,
                    float* __restrict__ C, int M, int N, int K, int gy) {
    __shared__ __align__(16) short As[64 * 32];     // 4 KB
    __shared__ __align__(16) short Bs[128 * 32];    // 8 KB
    const int tid = threadIdx.x;
    const int w = tid >> 6, l = tid & 63;
    const int lo = l & 15, hi = l >> 4;
    const int wr = w >> 1, wc = w & 1;

    const int flat = blockIdx.x;
    const int cpx = gridDim.x >> 3;
    const int s = (flat & 7) * cpx + (flat >> 3);
    const int by = s % gy, bx = s / gy;
    const size_t m0 = (size_t)by * 64;
    const size_t n0 = (size_t)bx * 128;

    const int crr = l >> 2;
    const int cc = (l & 3) * 8;
    const short* Ag  = A + (m0 + w * 16 + crr) * K + cc;
    const short* Bg0 = B + (n0 + (2 * w) * 16 + crr) * K + cc;
    const short* Bg1 = Bg0 + (size_t)16 * K;
    short* As0 = As + w * 512;
    short* Bs0 = Bs + (2 * w) * 512;
    short* Bs1 = Bs0 + 512;

    f32x4 acc[2][4];
    #pragma unroll
    for (int mi = 0; mi < 2; ++mi)
        #pragma unroll
        for (int nj = 0; nj < 4; ++nj)
            acc[mi][nj] = (f32x4){0.f, 0.f, 0.f, 0.f};

    const int aoff = (wr * 32 + lo) * 32 + hi * 8;
    const int boff = (wc * 64 + lo) * 32 + hi * 8;

    for (int k0 = 0; k0 < K; k0 += 32) {
        __syncthreads();
        gload16(Ag + k0, As0);
        gload16(Bg0 + k0, Bs0);
        gload16(Bg1 + k0, Bs1);
        __syncthreads();
        short8v af[2], bf[4];
        #pragma unroll
        for (int mi = 0; mi < 2; ++mi)
            af[mi] = *(const short8v*)&As[aoff + mi * 16 * 32];
        #pragma unroll
        for (int nj = 0; nj < 4; ++nj)
            bf[nj] = *(const short8v*)&Bs[boff + nj * 16 * 32];
        #pragma unroll
        for (int mi = 0; mi < 2; ++mi)
            #pragma unroll
            for (int nj = 0; nj < 4; ++nj)
                acc[mi][nj] = __builtin_amdgcn_mfma_f32_16x16x32_bf16(
                    af[mi], bf[nj], acc[mi][nj], 0, 0, 0);
    }

    const size_t mbase = m0 + wr * 32 + hi * 4;
    const size_t nbase = n0 + wc * 64 + lo;
    #pragma unroll
    for (int mi = 0; mi < 2; ++mi)
        #pragma unroll
        for (int nj = 0; nj < 4; ++nj)
            #pragma unroll
            for (int rg = 0; rg < 4; ++rg)
                C[(mbase + mi * 16 + rg) * N + nbase + nj * 16] =
                    acc[mi][nj][rg];
}

// ---------------------------------------------------------------------------
// rope_vt = fused {RoPE on Q/K} U {V -> blocked-transposed Vt2}. (passing)
// ---------------------------------------------------------------------------
__global__ __launch_bounds__(256)
void rope_vt(const short* __restrict__ QKVr, const float2* __restrict__ cst,
             short* __restrict__ Qh, short* __restrict__ Kh,
             short* __restrict__ Vt, int S, int rows, int ropeBlk) {
    __shared__ __align__(16) short T[64][72];
    const int tid = threadIdx.x;

    if ((int)blockIdx.x < ropeBlk) {
        int idx = blockIdx.x * 256 + tid;
        const int per = rows * (DM / 2);
        bool isK = false;
        if (idx >= per) { idx -= per; isK = true; }
        if (idx >= per) return;
        const int row = idx >> 9;
        const int rem = idx & 511;
        const int h = rem >> 5, k = rem & 31;
        const int b = row / S, sr = row - b * S;
        const unsigned pin = *(const unsigned*)(QKVr + (size_t)row * QKV +
                                                (isK ? DM : 0) + h * DH + 2 * k);
        const float x0 = __uint_as_float(pin << 16);
        const float x1 = __uint_as_float(pin & 0xffff0000u);
        const float2 cs = cst[sr * 32 + k];
        float y0 = cs.x * x0 - cs.y * x1;
        float y1 = cs.y * x0 + cs.x * x1;
        if (!isK) {
            const float qs = 0.125f * 1.4426950408889634f;
            y0 *= qs; y1 *= qs;
        }
        short* dst = (isK ? Kh : Qh) + ((size_t)(b * NH + h) * S + sr) * DH + 2 * k;
        *(unsigned*)dst = ((unsigned)(unsigned short)f2bf(y1) << 16)
                        | (unsigned short)f2bf(y0);
    } else {
        const int vb = blockIdx.x - ropeBlk;
        const int nsx = S >> 6;
        const int sx = vb % nsx, bh = vb / nsx;
        const int b = bh / NH, h = bh - b * NH;
        const int s0 = sx * 64;
        const int r = tid >> 2, seg = (tid & 3) * 16;
        const short* src = QKVr + (size_t)(b * S + s0 + r) * QKV + 2 * DM + h * DH + seg;
        const short8v a0 = *(const short8v*)(src);
        const short8v a1 = *(const short8v*)(src + 8);
        #pragma unroll
        for (int j = 0; j < 8; ++j) T[seg + j][r] = a0[j];
        #pragma unroll
        for (int j = 0; j < 8; ++j) T[seg + 8 + j][r] = a1[j];
        __syncthreads();
        const int d = tid >> 2, q = tid & 3;
        short* Vp2 = Vt + (size_t)bh * DH * S;
        #pragma unroll
        for (int j = 0; j < 2; ++j) {
            const int sbl = q * 2 + j;
            const uint4 v = *(const uint4*)&T[d][sbl * 8];
            *(uint4*)&Vp2[(((size_t)(s0 >> 3) + sbl) * 64 + d) * 8] = v;
        }
    }
}

// ---------------------------------------------------------------------------
// MFMA flash attention, R22 = R21 with the row-max shfl reduce HOISTED into
// the (cold) rescale branch: __any(pmax_local > m+8) is an equivalent
// trigger to __any(row_max > m+8) since __any spans the wave and m is
// row-synchronized; the xor16/xor32 reduce (4 serial cross-lane ops/iter)
// now runs only when the branch fires. Semantics bit-identical.
// ---------------------------------------------------------------------------
__global__ __launch_bounds__(256)
void attn_mfma(const short* __restrict__ Qh, const short* __restrict__ Kh,
               const short* __restrict__ Vt, short* __restrict__ Oh,
               int S, int bpb) {
    __shared__ __align__(16) unsigned P2[4][2][16][36];   // 18432 B
    __shared__ __align__(16) float MB[2][64][24];         // 12288 B

    const int tid = threadIdx.x;
    const int w = tid >> 6, l = tid & 63;
    const int pw = w >> 1, half = w & 1;
    const int lo = l & 15, hi = l >> 4;
    const int T = S >> 4;

    const int flat = blockIdx.x;
    const int bh3 = flat & 7;
    const int r = flat >> 3;
    const int grp = r / bpb, blk = r - grp * bpb;
    const int bh = grp * 8 + bh3;
    const int b = bh >> 4, h = bh & 15;          // NH = 16
    const int p = blk * 2 + pw;

    const int q0B = (T - 1 - p) << 4;
    const int q0F = p << 4;
    const int nkbB = (q0B + 79) >> 6;
    const int nkbF = (q0F + 79) >> 6;

    const short* Qp = Qh + (size_t)bh * S * DH;

    const short8v qB0 = *(const short8v*)(Qp + (size_t)(q0B + lo) * DH + hi * 8);
    const short8v qB1 = *(const short8v*)(Qp + (size_t)(q0B + lo) * DH + 32 + hi * 8);
    const short8v qF0 = *(const short8v*)(Qp + (size_t)(q0F + lo) * DH + hi * 8);
    const short8v qF1 = *(const short8v*)(Qp + (size_t)(q0F + lo) * DH + 32 + hi * 8);

    const short* kptr = Kh + (size_t)bh * S * DH
                      + (size_t)(half * 64 + lo) * DH + hi * 8;
    const short* vptr = Vt + (size_t)bh * DH * S
                      + (size_t)(half * 8 + hi) * 512 + lo * 8;

    short8v ones;
    #pragma unroll
    for (int i = 0; i < 8; ++i) ones[i] = (short)0x3F80;   // bf16 1.0

    f32x4 oB[4], oF[4];
    f32x4 laB = (f32x4){0.f, 0.f, 0.f, 0.f};
    f32x4 laF = (f32x4){0.f, 0.f, 0.f, 0.f};
    float mB = -INFINITY, mF = -INFINITY;
    #pragma unroll
    for (int i = 0; i < 4; ++i) {
        oB[i] = (f32x4){0.f, 0.f, 0.f, 0.f};
        oF[i] = (f32x4){0.f, 0.f, 0.f, 0.f};
    }
    const f32x4 z = (f32x4){0.f, 0.f, 0.f, 0.f};

    auto softmaxTile = [&](const f32x4 (&s)[4], float& m, f32x4 (&o)[4],
                           f32x4& la, bool masked, int q0, int kvb, int tsel) {
        float pv[16];
        float pmax = -INFINITY;
        const int lim = q0 + lo - kvb;
        #pragma unroll
        for (int kt = 0; kt < 4; ++kt)
            #pragma unroll
            for (int rg = 0; rg < 4; ++rg) {
                float v = s[kt][rg];
                if (masked && (kt * 16 + hi * 4 + rg > lim)) v = -INFINITY;
                pv[kt * 4 + rg] = v;
                pmax = fmaxf(pmax, v);
            }
        // trigger on LANE-LOCAL pmax (equivalent: __any spans the wave, m is
        // row-synced); full row reduce only inside the cold branch.
        if (__any(pmax > m + 8.0f)) {
            float bm = pmax;
            bm = fmaxf(bm, __shfl_xor(bm, 16));
            bm = fmaxf(bm, __shfl_xor(bm, 32));
            const float mn = fmaxf(m, bm);
            const float c = exp2f(m - mn);
            m = mn;
            #pragma unroll
            for (int rg = 0; rg < 4; ++rg) {
                const float cr = bperm_f(hi * 4 + rg, c);
                la[rg] *= cr;
                #pragma unroll
                for (int dt = 0; dt < 4; ++dt) o[dt][rg] *= cr;
            }
        }
        #pragma unroll
        for (int kt = 0; kt < 4; ++kt) {
            uint2 wv;
            wv.x = cvtpk(exp2f(pv[kt * 4 + 0] - m), exp2f(pv[kt * 4 + 1] - m));
            wv.y = cvtpk(exp2f(pv[kt * 4 + 2] - m), exp2f(pv[kt * 4 + 3] - m));
            *(uint2*)&P2[w][tsel][lo][kt * 8 + hi * 2] = wv;
        }
    };

    int kb = half;

    // ==== PHASE 1: both tiles active (kb < nkbF) ====
    for (; kb < nkbF; kb += 2) {
        const int kvb = kb * 64;

        short8v kf0[4], kf1[4];
        #pragma unroll
        for (int kt = 0; kt < 4; ++kt) {
            kf0[kt] = *(const short8v*)(kptr + kt * 1024);
            kf1[kt] = *(const short8v*)(kptr + kt * 1024 + 32);
        }

        f32x4 sB[4], sF[4];
        __builtin_amdgcn_s_setprio(1);
        #pragma unroll
        for (int kt = 0; kt < 4; ++kt) {
            f32x4 a = z;
            a = __builtin_amdgcn_mfma_f32_16x16x32_bf16(kf0[kt], qB0, a, 0, 0, 0);
            a = __builtin_amdgcn_mfma_f32_16x16x32_bf16(kf1[kt], qB1, a, 0, 0, 0);
            sB[kt] = a;
        }
        #pragma unroll
        for (int kt = 0; kt < 4; ++kt) {
            f32x4 a = z;
            a = __builtin_amdgcn_mfma_f32_16x16x32_bf16(kf0[kt], qF0, a, 0, 0, 0);
            a = __builtin_amdgcn_mfma_f32_16x16x32_bf16(kf1[kt], qF1, a, 0, 0, 0);
            sF[kt] = a;
        }
        __builtin_amdgcn_s_setprio(0);

        softmaxTile(sB, mB, oB, laB, false, q0B, kvb, 0);
        softmaxTile(sF, mF, oF, laF, kb == nkbF - 1, q0F, kvb, 1);

        short8v vf0[4], vf1[4];
        #pragma unroll
        for (int dt = 0; dt < 4; ++dt) {
            vf0[dt] = *(const short8v*)(vptr + dt * 128);
            vf1[dt] = *(const short8v*)(vptr + dt * 128 + 2048);
        }

        asm volatile("s_waitcnt lgkmcnt(0)" ::: "memory");
        const short8v paB0 = *(const short8v*)&P2[w][0][lo][hi * 4];
        const short8v paB1 = *(const short8v*)&P2[w][0][lo][16 + hi * 4];
        const short8v paF0 = *(const short8v*)&P2[w][1][lo][hi * 4];
        const short8v paF1 = *(const short8v*)&P2[w][1][lo][16 + hi * 4];

        __builtin_amdgcn_s_setprio(1);
        laB = __builtin_amdgcn_mfma_f32_16x16x32_bf16(paB0, ones, laB, 0, 0, 0);
        laB = __builtin_amdgcn_mfma_f32_16x16x32_bf16(paB1, ones, laB, 0, 0, 0);
        laF = __builtin_amdgcn_mfma_f32_16x16x32_bf16(paF0, ones, laF, 0, 0, 0);
        laF = __builtin_amdgcn_mfma_f32_16x16x32_bf16(paF1, ones, laF, 0, 0, 0);
        #pragma unroll
        for (int dt = 0; dt < 4; ++dt) {
            oB[dt] = __builtin_amdgcn_mfma_f32_16x16x32_bf16(paB0, vf0[dt], oB[dt], 0, 0, 0);
            oB[dt] = __builtin_amdgcn_mfma_f32_16x16x32_bf16(paB1, vf1[dt], oB[dt], 0, 0, 0);
            oF[dt] = __builtin_amdgcn_mfma_f32_16x16x32_bf16(paF0, vf0[dt], oF[dt], 0, 0, 0);
            oF[dt] = __builtin_amdgcn_mfma_f32_16x16x32_bf16(paF1, vf1[dt], oF[dt], 0, 0, 0);
        }
        __builtin_amdgcn_s_setprio(0);

        kptr += 8192;
        vptr += 8192;
    }

    // ==== PHASE 2: B tile only (nkbF <= kb < nkbB) ====
    for (; kb < nkbB; kb += 2) {
        const int kvb = kb * 64;

        short8v kf0[4], kf1[4];
        #pragma unroll
        for (int kt = 0; kt < 4; ++kt) {
            kf0[kt] = *(const short8v*)(kptr + kt * 1024);
            kf1[kt] = *(const short8v*)(kptr + kt * 1024 + 32);
        }

        f32x4 sB[4];
        __builtin_amdgcn_s_setprio(1);
        #pragma unroll
        for (int kt = 0; kt < 4; ++kt) {
            f32x4 a = z;
            a = __builtin_amdgcn_mfma_f32_16x16x32_bf16(kf0[kt], qB0, a, 0, 0, 0);
            a = __builtin_amdgcn_mfma_f32_16x16x32_bf16(kf1[kt], qB1, a, 0, 0, 0);
            sB[kt] = a;
        }
        __builtin_amdgcn_s_setprio(0);

        softmaxTile(sB, mB, oB, laB, kb == nkbB - 1, q0B, kvb, 0);

        short8v vf0[4], vf1[4];
        #pragma unroll
        for (int dt = 0; dt < 4; ++dt) {
            vf0[dt] = *(const short8v*)(vptr + dt * 128);
            vf1[dt] = *(const short8v*)(vptr + dt * 128 + 2048);
        }

        asm volatile("s_waitcnt lgkmcnt(0)" ::: "memory");
        const short8v paB0 = *(const short8v*)&P2[w][0][lo][hi * 4];
        const short8v paB1 = *(const short8v*)&P2[w][0][lo][16 + hi * 4];

        __builtin_amdgcn_s_setprio(1);
        laB = __builtin_amdgcn_mfma_f32_16x16x32_bf16(paB0, ones, laB, 0, 0, 0);
        laB = __builtin_amdgcn_mfma_f32_16x16x32_bf16(paB1, ones, laB, 0, 0, 0);
        #pragma unroll
        for (int dt = 0; dt < 4; ++dt) {
            oB[dt] = __builtin_amdgcn_mfma_f32_16x16x32_bf16(paB0, vf0[dt], oB[dt], 0, 0, 0);
            oB[dt] = __builtin_amdgcn_mfma_f32_16x16x32_bf16(paB1, vf1[dt], oB[dt], 0, 0, 0);
        }
        __builtin_amdgcn_s_setprio(0);

        kptr += 8192;
        vptr += 8192;
    }

    float mBr[4], mFr[4];
    #pragma unroll
    for (int rg = 0; rg < 4; ++rg) {
        mBr[rg] = bperm_f(hi * 4 + rg, mB);
        mFr[rg] = bperm_f(hi * 4 + rg, mF);
    }

#define STORE_TILE(OT, MT, LAT)                                            \
    do {                                                                   \
        f32x4* dst = (f32x4*)&MB[pw][l][0];                                \
        dst[0] = OT[0]; dst[1] = OT[1]; dst[2] = OT[2]; dst[3] = OT[3];    \
        dst[4] = (f32x4){MT[0], MT[1], MT[2], MT[3]};                      \
        dst[5] = LAT;                                                      \
    } while (0)

#define MERGE_TILE(OT, MT, LAT, Q0T)                                       \
    do {                                                                   \
        const f32x4* src = (const f32x4*)&MB[pw][l][0];                    \
        const f32x4 o1_0 = src[0], o1_1 = src[1], o1_2 = src[2], o1_3 = src[3]; \
        const f32x4 m1 = src[4];                                           \
        const f32x4 la1 = src[5];                                          \
        short* Op = Oh + (size_t)(b * S + (Q0T)) * DM + h * DH;            \
        _Pragma("unroll")                                                  \
        for (int rg = 0; rg < 4; ++rg) {                                   \
            const float mst = fmaxf(MT[rg], m1[rg]);                       \
            const float c0 = exp2f(MT[rg] - mst);                          \
            const float c1 = exp2f(m1[rg] - mst);                          \
            const float iv = 1.0f / (LAT[rg] * c0 + la1[rg] * c1);         \
            Op[(size_t)(hi * 4 + rg) * DM +  0 + lo] = f2bf((OT[0][rg] * c0 + o1_0[rg] * c1) * iv); \
            Op[(size_t)(hi * 4 + rg) * DM + 16 + lo] = f2bf((OT[1][rg] * c0 + o1_1[rg] * c1) * iv); \
            Op[(size_t)(hi * 4 + rg) * DM + 32 + lo] = f2bf((OT[2][rg] * c0 + o1_2[rg] * c1) * iv); \
            Op[(size_t)(hi * 4 + rg) * DM + 48 + lo] = f2bf((OT[3][rg] * c0 + o1_3[rg] * c1) * iv); \
        }                                                                  \
    } while (0)

    __syncthreads();
    if (half == 1) STORE_TILE(oB, mBr, laB);
    __syncthreads();
    if (half == 0) MERGE_TILE(oB, mBr, laB, q0B);
    __syncthreads();
    if (half == 1) STORE_TILE(oF, mFr, laF);
    __syncthreads();
    if (half == 0) MERGE_TILE(oF, mFr, laF, q0F);
#undef STORE_TILE
#undef MERGE_TILE
}

// ---------------------------------------------------------------------------
extern "C" void kernel_launch(void* const* d_in, const int* in_sizes, int n_in,
                              void* d_out, int out_size, void* d_ws, size_t ws_size,
                              hipStream_t stream) {
    const float* x  = (const float*)d_in[0];
    const int*  pos = (const int*)d_in[1];
    const float* wq = (const float*)d_in[2];
    const float* wk = (const float*)d_in[3];
    const float* wv = (const float*)d_in[4];
    const float* wo = (const float*)d_in[5];
    float* out = (float*)d_out;

    const int S = in_sizes[1];              // 2048
    const int rows = in_sizes[0] / DM;      // B*S
    const int Bb = rows / S;

    short* xh   = (short*)d_ws;
    short* wqkv = xh + (size_t)rows * DM;
    short* woh  = wqkv + (size_t)QKV * DM;
    short* QKVr = woh + (size_t)DM * DM;
    short* Qh   = QKVr + (size_t)rows * QKV;
    short* Kh   = Qh + (size_t)rows * DM;
    short* Vt   = Kh + (size_t)rows * DM;
    short* Oh   = Vt + (size_t)rows * DM;
    float2* cst = (float2*)(Oh + (size_t)rows * DM);

    const int nx = rows * DM;
    const int nw = DM * DM;
    const int nprep = (nx + 4 * nw) / 4 + S * 32;
    prep<<<(nprep + 255) / 256, 256, 0, stream>>>(
        x, wq, wk, wv, wo, pos, xh, wqkv, woh, cst, nx, nw, S);

    gemm_bt_mfma<1><<<dim3((QKV / 128) * (rows / 128)), 256, 0, stream>>>(
        xh, wqkv, QKVr, rows, QKV, DM, rows / 128);

    const int ropeBlk = (rows * DM + 255) / 256;
    const int vtBlk = (S / 64) * (Bb * NH);
    rope_vt<<<ropeBlk + vtBlk, 256, 0, stream>>>(
        QKVr, cst, Qh, Kh, Vt, S, rows, ropeBlk);

    const int Tq = S / 16;
    const int bpb = Tq / 4;
    const int nbh = Bb * NH;
    attn_mfma<<<dim3(nbh * bpb), 256, 0, stream>>>(Qh, Kh, Vt, Oh, S, bpb);

    gemm_bt_mfma64<<<dim3((DM / 128) * (rows / 64)), 256, 0, stream>>>(
        Oh, woh, out, rows, DM, DM, rows / 64);
}